// Round 11
// baseline (25.387 us; speedup 1.0000x reference)
//
#include <hip/hip_runtime.h>
#include <math.h>

#define T 512
#define EPS2 1e-4f
#define C0G 0.79788456f      // erf(x/sqrt2) = C0 x + C1 x^3 + C2 x^5 + C3 x^7
#define C1G (-0.13298076f)
#define C2G (0.019947114f)
#define C3G (-0.0023746564f)

typedef __attribute__((ext_vector_type(8))) short s8v;   // 8 bf16
typedef __attribute__((ext_vector_type(4))) float f4v;   // MFMA acc

__device__ __forceinline__ uint f2bf(float x){   // f32 -> bf16 bits, RNE
  uint u = __float_as_uint(x);
  return (u + 0x7FFFu + ((u>>16)&1u)) >> 16;
}
__device__ __forceinline__ uint pk2(float a, float b){ return f2bf(a)|(f2bf(b)<<16); }
__device__ __forceinline__ float bflo(uint u){ return __uint_as_float(u<<16); }
__device__ __forceinline__ float bfhi(uint u){ return __uint_as_float(u & 0xFFFF0000u); }
#define MFMA32 __builtin_amdgcn_mfma_f32_16x16x32_bf16
// truncated gelu core (0.5 applied by caller): gf(x) = x + C0 x^2 + C1 x^4
__device__ __forceinline__ float gf(float x){ float x2=x*x; return x + x2*fmaf(C1G,x2,C0G); }

// ws layout: [0, 10240) uints = 80 rows x 128 ushorts bf16 (Wl | Wat | Was);
// floats [5120, 5129) = K[9] softplus-arg polynomial coeffs.
#define WS_KOFF 5120

// ---------------- k_prep: fold weights + c-poly, once ----------------
__global__ __launch_bounds__(256) void k_prep(
    const float* __restrict__ Wl, const float* __restrict__ Wt,
    const float* __restrict__ pw1, const float* __restrict__ pb1,
    const float* __restrict__ pw2, const float* __restrict__ pb2,
    const float* __restrict__ twq, const float* __restrict__ tws,
    const float* __restrict__ twd, float* __restrict__ ws)
{
  const int tid = threadIdx.x;
  ushort* wsU = (ushort*)ws;
  // (a) Wl rows 0..15 (bf16)
  {
    const int j = tid>>4, k0 = (tid&15)*8;
    const float4* src = (const float4*)(Wl + j*128 + k0);
    const float4 b0 = src[0], b1 = src[1];
    uint4 v; v.x=pk2(b0.x,b0.y); v.y=pk2(b0.z,b0.w); v.z=pk2(b1.x,b1.y); v.w=pk2(b1.z,b1.w);
    *(uint4*)(wsU + j*128 + k0) = v;
  }
  // (b) fold: Wat=(twq+twd)Wt -> rows 16..47, Was=(tws-twd)Wt -> rows 48..79
  {
    const int j = tid>>3, k0 = (tid&7)*16;
    float twa[8], twb[8];
    #pragma unroll
    for (int m=0;m<8;m++){
      const float d = twd[j*8+m];
      twa[m] = twq[j*8+m] + d; twb[m] = tws[j*8+m] - d;
    }
    float oa[16], ob[16];
    #pragma unroll
    for (int i=0;i<16;i++){ oa[i]=0.f; ob[i]=0.f; }
    #pragma unroll
    for (int m=0;m<8;m++){
      const float4* wr = (const float4*)(Wt + m*128 + k0);
      const float ta = twa[m], tbv = twb[m];
      #pragma unroll
      for (int g=0; g<4; ++g){
        const float4 q = wr[g];
        oa[g*4+0]=fmaf(ta,q.x,oa[g*4+0]); ob[g*4+0]=fmaf(tbv,q.x,ob[g*4+0]);
        oa[g*4+1]=fmaf(ta,q.y,oa[g*4+1]); ob[g*4+1]=fmaf(tbv,q.y,ob[g*4+1]);
        oa[g*4+2]=fmaf(ta,q.z,oa[g*4+2]); ob[g*4+2]=fmaf(tbv,q.z,ob[g*4+2]);
        oa[g*4+3]=fmaf(ta,q.w,oa[g*4+3]); ob[g*4+3]=fmaf(tbv,q.w,ob[g*4+3]);
      }
    }
    uint4 v;
    v.x=pk2(oa[0],oa[1]); v.y=pk2(oa[2],oa[3]); v.z=pk2(oa[4],oa[5]); v.w=pk2(oa[6],oa[7]);
    *(uint4*)(wsU + (16+j)*128 + k0) = v;
    v.x=pk2(oa[8],oa[9]); v.y=pk2(oa[10],oa[11]); v.z=pk2(oa[12],oa[13]); v.w=pk2(oa[14],oa[15]);
    *(uint4*)(wsU + (16+j)*128 + k0 + 8) = v;
    v.x=pk2(ob[0],ob[1]); v.y=pk2(ob[2],ob[3]); v.z=pk2(ob[4],ob[5]); v.w=pk2(ob[6],ob[7]);
    *(uint4*)(wsU + (48+j)*128 + k0) = v;
    v.x=pk2(ob[8],ob[9]); v.y=pk2(ob[10],ob[11]); v.z=pk2(ob[12],ob[13]); v.w=pk2(ob[14],ob[15]);
    *(uint4*)(wsU + (48+j)*128 + k0 + 8) = v;
  }
  // (c) c(l2) polynomial coeffs
  if (tid < 64){
    const int lj = tid & 31;
    const float kw = (tid < 32) ? (0.5f * pw2[lj]) : 0.f;
    const float bb = pb1[lj], mm = pw1[lj];
    float bp[9], mp[9];
    bp[0]=1.f; mp[0]=1.f;
    #pragma unroll
    for (int i=1;i<9;i++){ bp[i]=bp[i-1]*bb; mp[i]=mp[i-1]*mm; }
    float K[9];
    K[0] = kw*(bb + C0G*bp[2] + C1G*bp[4] + C2G*bp[6] + C3G*bp[8]);
    K[1] = kw*mp[1]*(1.f + 2.f*C0G*bp[1] + 4.f*C1G*bp[3] + 6.f*C2G*bp[5] + 8.f*C3G*bp[7]);
    K[2] = kw*mp[2]*(C0G + 6.f*C1G*bp[2] + 15.f*C2G*bp[4] + 28.f*C3G*bp[6]);
    K[3] = kw*mp[3]*(4.f*C1G*bp[1] + 20.f*C2G*bp[3] + 56.f*C3G*bp[5]);
    K[4] = kw*mp[4]*(C1G + 15.f*C2G*bp[2] + 70.f*C3G*bp[4]);
    K[5] = kw*mp[5]*(6.f*C2G*bp[1] + 56.f*C3G*bp[3]);
    K[6] = kw*mp[6]*(C2G + 28.f*C3G*bp[2]);
    K[7] = kw*mp[7]*(8.f*C3G*bp[1]);
    K[8] = kw*mp[8]*C3G;
    #pragma unroll
    for (int m=1;m<64;m<<=1){
      #pragma unroll
      for (int i=0;i<9;i++) K[i] += __shfl_xor(K[i], m);
    }
    if (tid==0){
      K[0] += pb2[0];
      #pragma unroll
      for (int i=0;i<9;i++) ws[WS_KOFF + i] = K[i];
    }
  }
}

// LDS byte offsets (52224 total). Wb dead after P2 -> uvT/uvS overlay it.
#define L_HB  0        // 16384: s-tile, 1024 slots x 16B (persistent)
#define L_WB  16384    // 21120: 80 rows x 132 ush
#define L_UVT 16384    // 13312: 64 x 104 ush (overlays Wb)
#define L_UVS 29696    // 13312
#define L_LPT 43008    // 4096: 64 x 32 ush (cols 16..31 zero)
#define L_LPS 47104    // 4096
#define L_H2T 51200
#define L_H2S 51456
#define L_L2S 51712
#define L_BT  51968
#define L_TOT 52224

// ---------------- k_all: trimmed pipeline (3 syncs, no hA stage) -----------
__global__ __launch_bounds__(256,2) void k_all(
    const float* __restrict__ h, const float* __restrict__ hsrc,
    const float* __restrict__ tb1, const float* __restrict__ tw2,
    const float* __restrict__ tb2, const float* __restrict__ wsrc,
    float* __restrict__ out)
{
  __shared__ __align__(16) char smem[L_TOT];
  ushort* hB  = (ushort*)(smem + L_HB);
  ushort* Wb  = (ushort*)(smem + L_WB);
  ushort* uvT = (ushort*)(smem + L_UVT);
  ushort* uvS = (ushort*)(smem + L_UVS);
  ushort* lpT = (ushort*)(smem + L_LPT);
  ushort* lpS = (ushort*)(smem + L_LPS);
  float* h2nT = (float*)(smem + L_H2T);
  float* h2nS = (float*)(smem + L_H2S);
  float* l2nS = (float*)(smem + L_L2S);
  float* btS  = (float*)(smem + L_BT);

  const int tid = threadIdx.x;
  const int L   = blockIdx.x;
  const int blk = ((L & 7) << 6) | (L >> 3);   // XCD-affinity swizzle
  const int bs = (blk & 7)*64;
  const int bt = ((blk>>3)&7)*64;
  const int b  = blk>>6;
  const int lane = tid & 63, w = tid >> 6;
  const int hi = lane >> 4, c = lane & 15;

  // ================= P1: stage hB (s-tile) + Wb, load K ====================
  #pragma unroll
  for (int it=0; it<4; ++it){
    const int s = tid + it*256;
    const int q=s>>8, kk=(s>>6)&3, h2=(s>>4)&3, rr=s&15;
    const float4* src = (const float4*)(hsrc + (unsigned)(b*T + bs + q*16 + rr)*128u + kk*32 + h2*8);
    const float4 a0 = src[0], a1 = src[1];
    uint4 v; v.x=pk2(a0.x,a0.y); v.y=pk2(a0.z,a0.w); v.z=pk2(a1.x,a1.y); v.w=pk2(a1.z,a1.w);
    *(uint4*)(hB + s*8) = v;
  }
  {
    const ushort* wbs = (const ushort*)wsrc;
    #pragma unroll
    for (int i=tid; i<1280; i+=256){
      const int j = i>>4, k0 = (i&15)*8;
      *(uint4*)(Wb + j*132 + k0) = *(const uint4*)(wbs + j*128 + k0);
    }
  }
  float K[9];
  #pragma unroll
  for (int i=0;i<9;i++) K[i] = wsrc[WS_KOFF + i];
  __syncthreads();   // sync1

  // ================= P2: projections + reg-norms ===========================
  s8v ah[4];
  f4v pt[3], ps[3];
  #pragma unroll
  for (int i=0;i<3;i++){ pt[i]=(f4v){0,0,0,0}; ps[i]=(f4v){0,0,0,0}; }
  float nt = 0.f, ns = 0.f;
  const float* hT = h + (unsigned)(b*T + bt + w*16 + c)*128u;
  #pragma unroll
  for (int kk=0;kk<4;kk++){
    const float4* src = (const float4*)(hT + kk*32 + hi*8);
    const float4 a0 = src[0], a1 = src[1];
    union { uint4 u; s8v s; } U;
    U.u.x=pk2(a0.x,a0.y); U.u.y=pk2(a0.z,a0.w); U.u.z=pk2(a1.x,a1.y); U.u.w=pk2(a1.z,a1.w);
    ah[kk]=U.s;
    { float x;
      x=bflo(U.u.x); nt=fmaf(x,x,nt); x=bfhi(U.u.x); nt=fmaf(x,x,nt);
      x=bflo(U.u.y); nt=fmaf(x,x,nt); x=bfhi(U.u.y); nt=fmaf(x,x,nt);
      x=bflo(U.u.z); nt=fmaf(x,x,nt); x=bfhi(U.u.z); nt=fmaf(x,x,nt);
      x=bflo(U.u.w); nt=fmaf(x,x,nt); x=bfhi(U.u.w); nt=fmaf(x,x,nt); }
    union { s8v s; uint4 u; } V;
    V.s = *(const s8v*)(hB + (w*256 + kk*64 + lane)*8);
    { float x;
      x=bflo(V.u.x); ns=fmaf(x,x,ns); x=bfhi(V.u.x); ns=fmaf(x,x,ns);
      x=bflo(V.u.y); ns=fmaf(x,x,ns); x=bfhi(V.u.y); ns=fmaf(x,x,ns);
      x=bflo(V.u.z); ns=fmaf(x,x,ns); x=bfhi(V.u.z); ns=fmaf(x,x,ns);
      x=bflo(V.u.w); ns=fmaf(x,x,ns); x=bfhi(V.u.w); ns=fmaf(x,x,ns); }
    const int ko = kk*32 + hi*8;
    const s8v bl  = *(const s8v*)(Wb + (c)*132    + ko);
    const s8v bt0 = *(const s8v*)(Wb + (16+c)*132 + ko);
    const s8v bt1 = *(const s8v*)(Wb + (32+c)*132 + ko);
    const s8v bs0 = *(const s8v*)(Wb + (48+c)*132 + ko);
    const s8v bs1 = *(const s8v*)(Wb + (64+c)*132 + ko);
    pt[0]=MFMA32(ah[kk], bt0, pt[0],0,0,0);
    pt[1]=MFMA32(ah[kk], bt1, pt[1],0,0,0);
    pt[2]=MFMA32(ah[kk], bl,  pt[2],0,0,0);
    ps[0]=MFMA32(V.s, bs0, ps[0],0,0,0);
    ps[1]=MFMA32(V.s, bs1, ps[1],0,0,0);
    ps[2]=MFMA32(V.s, bl,  ps[2],0,0,0);
  }
  nt += __shfl_xor(nt,16); nt += __shfl_xor(nt,32);
  ns += __shfl_xor(ns,16); ns += __shfl_xor(ns,32);
  if (hi==0){ h2nT[w*16+c] = nt; h2nS[w*16+c] = ns; }
  __syncthreads();   // sync2: Wb dead -> uvT/uvS usable; h2n published

  // ================= P3: nonlinears + packs (single phase) =================
  const float tb1a = tb1[c], tb1b = tb1[c+16];
  const float w2a = tw2[c],  w2b = tw2[c+16];
  const float tb2v = tb2[0];
  float alpha[4], l2nt[4];
  #pragma unroll
  for (int r=0;r<4;r++){
    const int row = w*16 + hi*4 + r;
    const float a0 = pt[0][r] + tb1a, a1 = pt[1][r] + tb1b;
    const float b0 = ps[0][r],        b1 = ps[1][r];
    const float lv = pt[2][r],        lsv = ps[2][r];
    float pa  = fmaf(w2a, gf(a0), w2b*gf(a1));
    float pb_ = fmaf(w2a, gf(b0), w2b*gf(b1));
    float pl  = lv*lv, pls = lsv*lsv;
    #pragma unroll
    for (int m=1;m<16;m<<=1){
      pa  += __shfl_xor(pa,m);  pb_ += __shfl_xor(pb_,m);
      pl  += __shfl_xor(pl,m);  pls += __shfl_xor(pls,m);
    }
    alpha[r] = 0.5f*pa + tb2v;
    l2nt[r]  = pl;
    if (c==0){ btS[row] = 0.5f*pb_; l2nS[row] = pls; }
    lpT[row*32 + c] = (ushort)f2bf(lv);   lpT[row*32 + 16 + c] = 0;
    lpS[row*32 + c] = (ushort)f2bf(lsv);  lpS[row*32 + 16 + c] = 0;
    const float b02=b0*b0, b1_2=b1*b1;
    uvS[row*104 +      c] = (ushort)f2bf(b0);      uvS[row*104 + 16 + c] = (ushort)f2bf(b1);
    uvS[row*104 + 32 + c] = (ushort)f2bf(b02);     uvS[row*104 + 48 + c] = (ushort)f2bf(b1_2);
    uvS[row*104 + 64 + c] = (ushort)f2bf(b02*b0);  uvS[row*104 + 80 + c] = (ushort)f2bf(b1_2*b1);
    const float a02=a0*a0, a12=a1*a1;
    const float wa0 = w2a*a0, wa1 = w2b*a1;
    uvT[row*104 +      c] = (ushort)f2bf(wa0*fmaf(2.f*C1G, a02, C0G));
    uvT[row*104 + 16 + c] = (ushort)f2bf(wa1*fmaf(2.f*C1G, a12, C0G));
    uvT[row*104 + 32 + c] = (ushort)f2bf(3.f*C1G*w2a*a02);
    uvT[row*104 + 48 + c] = (ushort)f2bf(3.f*C1G*w2b*a12);
    uvT[row*104 + 64 + c] = (ushort)f2bf(2.f*C1G*wa0);
    uvT[row*104 + 80 + c] = (ushort)f2bf(2.f*C1G*wa1);
  }
  __syncthreads();   // sync3

  // ================= P4: pair MFMAs + epilogue =============================
  f4v acch[4], accz[4], accl[4];
  #pragma unroll
  for (int q=0;q<4;q++){ acch[q]=(f4v){0,0,0,0}; accz[q]=(f4v){0,0,0,0}; accl[q]=(f4v){0,0,0,0}; }
  #pragma unroll
  for (int kk=0;kk<4;kk++){
    #pragma unroll
    for (int q=0;q<4;q++)
      acch[q] = MFMA32(ah[kk], *(const s8v*)(hB + (q*256 + kk*64 + lane)*8), acch[q],0,0,0);
  }
  #pragma unroll
  for (int ks=0;ks<3;ks++){
    const s8v au = *(const s8v*)(uvT + (w*16 + c)*104 + ks*32 + hi*8);
    #pragma unroll
    for (int q=0;q<4;q++)
      accz[q] = MFMA32(au, *(const s8v*)(uvS + (16*q + c)*104 + ks*32 + hi*8), accz[q],0,0,0);
  }
  {
    const s8v al_ = *(const s8v*)(lpT + (w*16 + c)*32 + hi*8);
    #pragma unroll
    for (int q=0;q<4;q++)
      accl[q] = MFMA32(al_, *(const s8v*)(lpS + (16*q + c)*32 + hi*8), accl[q],0,0,0);
  }
  float h2t[4];
  #pragma unroll
  for (int r=0;r<4;r++) h2t[r] = h2nT[w*16 + hi*4 + r];
  #pragma unroll
  for (int q=0;q<4;q++){
    const int sidx = 16*q + c;
    const float h2s = h2nS[sidx], l2s = l2nS[sidx], bet = btS[sidx];
    #pragma unroll
    for (int r=0;r<4;r++){
      const float d2 = fmaxf(fmaf(-2.f, acch[q][r], h2t[r] + h2s), 0.f);
      const float ir = rsqrtf(d2 + EPS2);
      const float l2 = fmaxf(fmaf(-2.f, accl[q][r], l2nt[r] + l2s), 0.f);
      const float lam = fminf(l2, 16.f);
      float zc = K[8];
      #pragma unroll
      for (int i=7;i>=0;i--) zc = fmaf(zc, lam, K[i]);
      const float cc  = __logf(1.f + __expf(zc));         // softplus
      const float phi = __expf(-cc * l2);
      const float z   = accz[q][r] + alpha[r] + bet;
      const float th  = z * fmaf(z*z, -0.33333334f, 1.f); // tanh, |z| small
      out[(unsigned)(b*T + bt + w*16 + hi*4 + r)*T + bs + sidx] = -th * phi * ir;
    }
  }
}

extern "C" void kernel_launch(void* const* d_in, const int* in_sizes, int n_in,
                              void* d_out, int out_size, void* d_ws, size_t ws_size,
                              hipStream_t stream) {
  const float* h    = (const float*)d_in[0];
  const float* hsrc = (const float*)d_in[1];
  const float* Wl   = (const float*)d_in[2];
  const float* Wt   = (const float*)d_in[3];
  const float* pw1  = (const float*)d_in[4];
  const float* pb1  = (const float*)d_in[5];
  const float* pw2  = (const float*)d_in[6];
  const float* pb2  = (const float*)d_in[7];
  const float* twq  = (const float*)d_in[8];
  const float* tws  = (const float*)d_in[9];
  const float* twd  = (const float*)d_in[10];
  const float* tb1  = (const float*)d_in[11];
  const float* tw2  = (const float*)d_in[12];
  const float* tb2  = (const float*)d_in[13];
  float* ws  = (float*)d_ws;
  float* out = (float*)d_out;

  k_prep<<<dim3(1,1,1),   dim3(256,1,1), 0, stream>>>(Wl,Wt,pw1,pb1,pw2,pb2,twq,tws,twd,ws);
  k_all <<<dim3(512,1,1), dim3(256,1,1), 0, stream>>>(h,hsrc,tb1,tw2,tb2,ws,out);
}

// Round 12
// 25.020 us; speedup vs baseline: 1.0147x; 1.0147x over previous
//
#include <hip/hip_runtime.h>
#include <math.h>

#define T 512
#define EPS2 1e-4f
#define C0G 0.79788456f      // erf(x/sqrt2) = C0 x + C1 x^3 + C2 x^5 + C3 x^7
#define C1G (-0.13298076f)
#define C2G (0.019947114f)
#define C3G (-0.0023746564f)

typedef __attribute__((ext_vector_type(8))) short s8v;   // 8 bf16
typedef __attribute__((ext_vector_type(4))) float f4v;   // MFMA acc

__device__ __forceinline__ uint f2bf(float x){   // f32 -> bf16 bits, RNE
  uint u = __float_as_uint(x);
  return (u + 0x7FFFu + ((u>>16)&1u)) >> 16;
}
__device__ __forceinline__ uint pk2(float a, float b){ return f2bf(a)|(f2bf(b)<<16); }
__device__ __forceinline__ float bflo(uint u){ return __uint_as_float(u<<16); }
__device__ __forceinline__ float bfhi(uint u){ return __uint_as_float(u & 0xFFFF0000u); }
#define MFMA32 __builtin_amdgcn_mfma_f32_16x16x32_bf16
// truncated gelu core (0.5 applied by caller): gf(x) = x + C0 x^2 + C1 x^4
__device__ __forceinline__ float gf(float x){ float x2=x*x; return x + x2*fmaf(C1G,x2,C0G); }

// ws layout: [0, 10240) uints = 80 rows x 128 ushorts bf16 (Wl | Wat | Was);
// floats [5120, 5129) = K[9] softplus-arg polynomial coeffs.
#define WS_KOFF 5120

// ---------------- k_prep: fold weights + c-poly, once ----------------
__global__ __launch_bounds__(256) void k_prep(
    const float* __restrict__ Wl, const float* __restrict__ Wt,
    const float* __restrict__ pw1, const float* __restrict__ pb1,
    const float* __restrict__ pw2, const float* __restrict__ pb2,
    const float* __restrict__ twq, const float* __restrict__ tws,
    const float* __restrict__ twd, float* __restrict__ ws)
{
  const int tid = threadIdx.x;
  ushort* wsU = (ushort*)ws;
  // (a) Wl rows 0..15 (bf16)
  {
    const int j = tid>>4, k0 = (tid&15)*8;
    const float4* src = (const float4*)(Wl + j*128 + k0);
    const float4 b0 = src[0], b1 = src[1];
    uint4 v; v.x=pk2(b0.x,b0.y); v.y=pk2(b0.z,b0.w); v.z=pk2(b1.x,b1.y); v.w=pk2(b1.z,b1.w);
    *(uint4*)(wsU + j*128 + k0) = v;
  }
  // (b) fold: Wat=(twq+twd)Wt -> rows 16..47, Was=(tws-twd)Wt -> rows 48..79
  {
    const int j = tid>>3, k0 = (tid&7)*16;
    float twa[8], twb[8];
    #pragma unroll
    for (int m=0;m<8;m++){
      const float d = twd[j*8+m];
      twa[m] = twq[j*8+m] + d; twb[m] = tws[j*8+m] - d;
    }
    float oa[16], ob[16];
    #pragma unroll
    for (int i=0;i<16;i++){ oa[i]=0.f; ob[i]=0.f; }
    #pragma unroll
    for (int m=0;m<8;m++){
      const float4* wr = (const float4*)(Wt + m*128 + k0);
      const float ta = twa[m], tbv = twb[m];
      #pragma unroll
      for (int g=0; g<4; ++g){
        const float4 q = wr[g];
        oa[g*4+0]=fmaf(ta,q.x,oa[g*4+0]); ob[g*4+0]=fmaf(tbv,q.x,ob[g*4+0]);
        oa[g*4+1]=fmaf(ta,q.y,oa[g*4+1]); ob[g*4+1]=fmaf(tbv,q.y,ob[g*4+1]);
        oa[g*4+2]=fmaf(ta,q.z,oa[g*4+2]); ob[g*4+2]=fmaf(tbv,q.z,ob[g*4+2]);
        oa[g*4+3]=fmaf(ta,q.w,oa[g*4+3]); ob[g*4+3]=fmaf(tbv,q.w,ob[g*4+3]);
      }
    }
    uint4 v;
    v.x=pk2(oa[0],oa[1]); v.y=pk2(oa[2],oa[3]); v.z=pk2(oa[4],oa[5]); v.w=pk2(oa[6],oa[7]);
    *(uint4*)(wsU + (16+j)*128 + k0) = v;
    v.x=pk2(oa[8],oa[9]); v.y=pk2(oa[10],oa[11]); v.z=pk2(oa[12],oa[13]); v.w=pk2(oa[14],oa[15]);
    *(uint4*)(wsU + (16+j)*128 + k0 + 8) = v;
    v.x=pk2(ob[0],ob[1]); v.y=pk2(ob[2],ob[3]); v.z=pk2(ob[4],ob[5]); v.w=pk2(ob[6],ob[7]);
    *(uint4*)(wsU + (48+j)*128 + k0) = v;
    v.x=pk2(ob[8],ob[9]); v.y=pk2(ob[10],ob[11]); v.z=pk2(ob[12],ob[13]); v.w=pk2(ob[14],ob[15]);
    *(uint4*)(wsU + (48+j)*128 + k0 + 8) = v;
  }
  // (c) c(l2) polynomial coeffs
  if (tid < 64){
    const int lj = tid & 31;
    const float kw = (tid < 32) ? (0.5f * pw2[lj]) : 0.f;
    const float bb = pb1[lj], mm = pw1[lj];
    float bp[9], mp[9];
    bp[0]=1.f; mp[0]=1.f;
    #pragma unroll
    for (int i=1;i<9;i++){ bp[i]=bp[i-1]*bb; mp[i]=mp[i-1]*mm; }
    float K[9];
    K[0] = kw*(bb + C0G*bp[2] + C1G*bp[4] + C2G*bp[6] + C3G*bp[8]);
    K[1] = kw*mp[1]*(1.f + 2.f*C0G*bp[1] + 4.f*C1G*bp[3] + 6.f*C2G*bp[5] + 8.f*C3G*bp[7]);
    K[2] = kw*mp[2]*(C0G + 6.f*C1G*bp[2] + 15.f*C2G*bp[4] + 28.f*C3G*bp[6]);
    K[3] = kw*mp[3]*(4.f*C1G*bp[1] + 20.f*C2G*bp[3] + 56.f*C3G*bp[5]);
    K[4] = kw*mp[4]*(C1G + 15.f*C2G*bp[2] + 70.f*C3G*bp[4]);
    K[5] = kw*mp[5]*(6.f*C2G*bp[1] + 56.f*C3G*bp[3]);
    K[6] = kw*mp[6]*(C2G + 28.f*C3G*bp[2]);
    K[7] = kw*mp[7]*(8.f*C3G*bp[1]);
    K[8] = kw*mp[8]*C3G;
    #pragma unroll
    for (int m=1;m<64;m<<=1){
      #pragma unroll
      for (int i=0;i<9;i++) K[i] += __shfl_xor(K[i], m);
    }
    if (tid==0){
      K[0] += pb2[0];
      #pragma unroll
      for (int i=0;i<9;i++) ws[WS_KOFF + i] = K[i];
    }
  }
}

// LDS byte offsets (59392 total).
// hA dead after P2 -> lpT/lpS/row-arrays overlay it.
// Wb dead after P2 -> uvT/uvS overlay it.
#define L_HA  0        // 16384: t-tile, 1024 slots x 16B
#define L_LPT 0        // 4096: 64 x 32 ush (overlays hA)
#define L_LPS 4096     // 4096
#define L_H2T 8192     // 4 x 64 f32 arrays
#define L_H2S 8448
#define L_L2S 8704
#define L_BT  8960
#define L_HB  16384    // 16384: s-tile (persistent)
#define L_WB  32768    // 21120: 80 rows x 132 ush
#define L_UVT 32768    // 13312: 64 x 104 ush (overlays Wb)
#define L_UVS 46080    // 13312
#define L_TOT 59392

// ---------------- k_all: coalesced staging, all fragments via LDS ----------
__global__ __launch_bounds__(256,2) void k_all(
    const float* __restrict__ h, const float* __restrict__ hsrc,
    const float* __restrict__ tb1, const float* __restrict__ tw2,
    const float* __restrict__ tb2, const float* __restrict__ wsrc,
    float* __restrict__ out)
{
  __shared__ __align__(16) char smem[L_TOT];
  ushort* hA  = (ushort*)(smem + L_HA);
  ushort* hB  = (ushort*)(smem + L_HB);
  ushort* Wb  = (ushort*)(smem + L_WB);
  ushort* uvT = (ushort*)(smem + L_UVT);
  ushort* uvS = (ushort*)(smem + L_UVS);
  ushort* lpT = (ushort*)(smem + L_LPT);
  ushort* lpS = (ushort*)(smem + L_LPS);
  float* h2nT = (float*)(smem + L_H2T);
  float* h2nS = (float*)(smem + L_H2S);
  float* l2nS = (float*)(smem + L_L2S);
  float* btS  = (float*)(smem + L_BT);

  const int tid = threadIdx.x;
  const int L   = blockIdx.x;
  const int blk = ((L & 7) << 6) | (L >> 3);   // XCD-affinity swizzle
  const int bs = (blk & 7)*64;
  const int bt = ((blk>>3)&7)*64;
  const int b  = blk>>6;
  const int lane = tid & 63, w = tid >> 6;
  const int hi = lane >> 4, c = lane & 15;

  // ================= P1: COALESCED staging of both tiles + Wb ==============
  // i = side(1) | row(6) | cid(4): consecutive lanes read consecutive 32B of
  // the same f32 row (wave = 4 rows x 512B contiguous). LDS slot order is the
  // MFMA fragment order (slot = q*256 + kk*64 + h2*16 + rr).
  #pragma unroll
  for (int it=0; it<8; ++it){
    const int i = tid + it*256;
    const int side = i >> 10, i1 = i & 1023;
    const int row = i1 >> 4, cid = i1 & 15;
    const int kk = cid >> 2, h2 = cid & 3;
    const float4* src = (const float4*)((side? hsrc : h)
        + (unsigned)(b*T + (side? bs : bt) + row)*128u + kk*32 + h2*8);
    const float4 a0 = src[0], a1 = src[1];
    uint4 v; v.x=pk2(a0.x,a0.y); v.y=pk2(a0.z,a0.w); v.z=pk2(a1.x,a1.y); v.w=pk2(a1.z,a1.w);
    const int slot = (row>>4)*256 + kk*64 + h2*16 + (row&15);
    *(uint4*)((side? hB : hA) + slot*8) = v;
  }
  {
    const ushort* wbs = (const ushort*)wsrc;
    #pragma unroll
    for (int i=tid; i<1280; i+=256){
      const int j = i>>4, k0 = (i&15)*8;
      *(uint4*)(Wb + j*132 + k0) = *(const uint4*)(wbs + j*128 + k0);
    }
  }
  float K[9];
  #pragma unroll
  for (int i=0;i<9;i++) K[i] = wsrc[WS_KOFF + i];
  __syncthreads();   // sync1

  // ================= P2: projections + reg-norms ===========================
  s8v ah[4];
  f4v pt[3], ps[3];
  #pragma unroll
  for (int i=0;i<3;i++){ pt[i]=(f4v){0,0,0,0}; ps[i]=(f4v){0,0,0,0}; }
  float nt = 0.f, ns = 0.f;
  #pragma unroll
  for (int kk=0;kk<4;kk++){
    union { s8v s; uint4 u; } U;
    U.s = *(const s8v*)(hA + (w*256 + kk*64 + lane)*8);
    ah[kk] = U.s;
    { float x;
      x=bflo(U.u.x); nt=fmaf(x,x,nt); x=bfhi(U.u.x); nt=fmaf(x,x,nt);
      x=bflo(U.u.y); nt=fmaf(x,x,nt); x=bfhi(U.u.y); nt=fmaf(x,x,nt);
      x=bflo(U.u.z); nt=fmaf(x,x,nt); x=bfhi(U.u.z); nt=fmaf(x,x,nt);
      x=bflo(U.u.w); nt=fmaf(x,x,nt); x=bfhi(U.u.w); nt=fmaf(x,x,nt); }
    union { s8v s; uint4 u; } V;
    V.s = *(const s8v*)(hB + (w*256 + kk*64 + lane)*8);
    { float x;
      x=bflo(V.u.x); ns=fmaf(x,x,ns); x=bfhi(V.u.x); ns=fmaf(x,x,ns);
      x=bflo(V.u.y); ns=fmaf(x,x,ns); x=bfhi(V.u.y); ns=fmaf(x,x,ns);
      x=bflo(V.u.z); ns=fmaf(x,x,ns); x=bfhi(V.u.z); ns=fmaf(x,x,ns);
      x=bflo(V.u.w); ns=fmaf(x,x,ns); x=bfhi(V.u.w); ns=fmaf(x,x,ns); }
    const int ko = kk*32 + hi*8;
    const s8v bl  = *(const s8v*)(Wb + (c)*132    + ko);
    const s8v bt0 = *(const s8v*)(Wb + (16+c)*132 + ko);
    const s8v bt1 = *(const s8v*)(Wb + (32+c)*132 + ko);
    const s8v bs0 = *(const s8v*)(Wb + (48+c)*132 + ko);
    const s8v bs1 = *(const s8v*)(Wb + (64+c)*132 + ko);
    pt[0]=MFMA32(ah[kk], bt0, pt[0],0,0,0);
    pt[1]=MFMA32(ah[kk], bt1, pt[1],0,0,0);
    pt[2]=MFMA32(ah[kk], bl,  pt[2],0,0,0);
    ps[0]=MFMA32(V.s, bs0, ps[0],0,0,0);
    ps[1]=MFMA32(V.s, bs1, ps[1],0,0,0);
    ps[2]=MFMA32(V.s, bl,  ps[2],0,0,0);
  }
  nt += __shfl_xor(nt,16); nt += __shfl_xor(nt,32);
  ns += __shfl_xor(ns,16); ns += __shfl_xor(ns,32);
  __syncthreads();   // sync2: hA/Wb dead -> overlays usable
  if (hi==0){ h2nT[w*16+c] = nt; h2nS[w*16+c] = ns; }

  // ================= P3: nonlinears + packs (single phase) =================
  const float tb1a = tb1[c], tb1b = tb1[c+16];
  const float w2a = tw2[c],  w2b = tw2[c+16];
  const float tb2v = tb2[0];
  float alpha[4], l2nt[4];
  #pragma unroll
  for (int r=0;r<4;r++){
    const int row = w*16 + hi*4 + r;
    const float a0 = pt[0][r] + tb1a, a1 = pt[1][r] + tb1b;
    const float b0 = ps[0][r],        b1 = ps[1][r];
    const float lv = pt[2][r],        lsv = ps[2][r];
    float pa  = fmaf(w2a, gf(a0), w2b*gf(a1));
    float pb_ = fmaf(w2a, gf(b0), w2b*gf(b1));
    float pl  = lv*lv, pls = lsv*lsv;
    #pragma unroll
    for (int m=1;m<16;m<<=1){
      pa  += __shfl_xor(pa,m);  pb_ += __shfl_xor(pb_,m);
      pl  += __shfl_xor(pl,m);  pls += __shfl_xor(pls,m);
    }
    alpha[r] = 0.5f*pa + tb2v;
    l2nt[r]  = pl;
    if (c==0){ btS[row] = 0.5f*pb_; l2nS[row] = pls; }
    lpT[row*32 + c] = (ushort)f2bf(lv);   lpT[row*32 + 16 + c] = 0;
    lpS[row*32 + c] = (ushort)f2bf(lsv);  lpS[row*32 + 16 + c] = 0;
    const float b02=b0*b0, b1_2=b1*b1;
    uvS[row*104 +      c] = (ushort)f2bf(b0);      uvS[row*104 + 16 + c] = (ushort)f2bf(b1);
    uvS[row*104 + 32 + c] = (ushort)f2bf(b02);     uvS[row*104 + 48 + c] = (ushort)f2bf(b1_2);
    uvS[row*104 + 64 + c] = (ushort)f2bf(b02*b0);  uvS[row*104 + 80 + c] = (ushort)f2bf(b1_2*b1);
    const float a02=a0*a0, a12=a1*a1;
    const float wa0 = w2a*a0, wa1 = w2b*a1;
    uvT[row*104 +      c] = (ushort)f2bf(wa0*fmaf(2.f*C1G, a02, C0G));
    uvT[row*104 + 16 + c] = (ushort)f2bf(wa1*fmaf(2.f*C1G, a12, C0G));
    uvT[row*104 + 32 + c] = (ushort)f2bf(3.f*C1G*w2a*a02);
    uvT[row*104 + 48 + c] = (ushort)f2bf(3.f*C1G*w2b*a12);
    uvT[row*104 + 64 + c] = (ushort)f2bf(2.f*C1G*wa0);
    uvT[row*104 + 80 + c] = (ushort)f2bf(2.f*C1G*wa1);
  }
  __syncthreads();   // sync3

  // ================= P4: pair MFMAs + epilogue =============================
  f4v acch[4], accz[4], accl[4];
  #pragma unroll
  for (int q=0;q<4;q++){ acch[q]=(f4v){0,0,0,0}; accz[q]=(f4v){0,0,0,0}; accl[q]=(f4v){0,0,0,0}; }
  #pragma unroll
  for (int kk=0;kk<4;kk++){
    #pragma unroll
    for (int q=0;q<4;q++)
      acch[q] = MFMA32(ah[kk], *(const s8v*)(hB + (q*256 + kk*64 + lane)*8), acch[q],0,0,0);
  }
  #pragma unroll
  for (int ks=0;ks<3;ks++){
    const s8v au = *(const s8v*)(uvT + (w*16 + c)*104 + ks*32 + hi*8);
    #pragma unroll
    for (int q=0;q<4;q++)
      accz[q] = MFMA32(au, *(const s8v*)(uvS + (16*q + c)*104 + ks*32 + hi*8), accz[q],0,0,0);
  }
  {
    const s8v al_ = *(const s8v*)(lpT + (w*16 + c)*32 + hi*8);
    #pragma unroll
    for (int q=0;q<4;q++)
      accl[q] = MFMA32(al_, *(const s8v*)(lpS + (16*q + c)*32 + hi*8), accl[q],0,0,0);
  }
  float h2t[4];
  #pragma unroll
  for (int r=0;r<4;r++) h2t[r] = h2nT[w*16 + hi*4 + r];
  #pragma unroll
  for (int q=0;q<4;q++){
    const int sidx = 16*q + c;
    const float h2s = h2nS[sidx], l2s = l2nS[sidx], bet = btS[sidx];
    #pragma unroll
    for (int r=0;r<4;r++){
      const float d2 = fmaxf(fmaf(-2.f, acch[q][r], h2t[r] + h2s), 0.f);
      const float ir = rsqrtf(d2 + EPS2);
      const float l2 = fmaxf(fmaf(-2.f, accl[q][r], l2nt[r] + l2s), 0.f);
      const float lam = fminf(l2, 16.f);
      float zc = K[8];
      #pragma unroll
      for (int i=7;i>=0;i--) zc = fmaf(zc, lam, K[i]);
      const float cc  = __logf(1.f + __expf(zc));         // softplus
      const float phi = __expf(-cc * l2);
      const float z   = accz[q][r] + alpha[r] + bet;
      const float th  = z * fmaf(z*z, -0.33333334f, 1.f); // tanh, |z| small
      out[(unsigned)(b*T + bt + w*16 + hi*4 + r)*T + bs + sidx] = -th * phi * ir;
    }
  }
}

extern "C" void kernel_launch(void* const* d_in, const int* in_sizes, int n_in,
                              void* d_out, int out_size, void* d_ws, size_t ws_size,
                              hipStream_t stream) {
  const float* h    = (const float*)d_in[0];
  const float* hsrc = (const float*)d_in[1];
  const float* Wl   = (const float*)d_in[2];
  const float* Wt   = (const float*)d_in[3];
  const float* pw1  = (const float*)d_in[4];
  const float* pb1  = (const float*)d_in[5];
  const float* pw2  = (const float*)d_in[6];
  const float* pb2  = (const float*)d_in[7];
  const float* twq  = (const float*)d_in[8];
  const float* tws  = (const float*)d_in[9];
  const float* twd  = (const float*)d_in[10];
  const float* tb1  = (const float*)d_in[11];
  const float* tw2  = (const float*)d_in[12];
  const float* tb2  = (const float*)d_in[13];
  float* ws  = (float*)d_ws;
  float* out = (float*)d_out;

  k_prep<<<dim3(1,1,1),   dim3(256,1,1), 0, stream>>>(Wl,Wt,pw1,pb1,pw2,pb2,twq,tws,twd,ws);
  k_all <<<dim3(512,1,1), dim3(256,1,1), 0, stream>>>(h,hsrc,tb1,tw2,tb2,ws,out);
}

// Round 13
// 23.873 us; speedup vs baseline: 1.0634x; 1.0480x over previous
//
#include <hip/hip_runtime.h>
#include <math.h>

#define T 512
#define EPS2 1e-4f
#define C0G 0.79788456f      // erf(x/sqrt2) = C0 x + C1 x^3 + C2 x^5 + C3 x^7
#define C1G (-0.13298076f)
#define C2G (0.019947114f)
#define C3G (-0.0023746564f)

typedef __attribute__((ext_vector_type(8))) short s8v;   // 8 bf16
typedef __attribute__((ext_vector_type(4))) float f4v;   // MFMA acc

__device__ __forceinline__ uint f2bf(float x){   // f32 -> bf16 bits, RNE
  uint u = __float_as_uint(x);
  return (u + 0x7FFFu + ((u>>16)&1u)) >> 16;
}
__device__ __forceinline__ uint pk2(float a, float b){ return f2bf(a)|(f2bf(b)<<16); }
__device__ __forceinline__ float bflo(uint u){ return __uint_as_float(u<<16); }
__device__ __forceinline__ float bfhi(uint u){ return __uint_as_float(u & 0xFFFF0000u); }
#define MFMA32 __builtin_amdgcn_mfma_f32_16x16x32_bf16
// truncated gelu core (0.5 applied by caller): gf(x) = x + C0 x^2 + C1 x^4
__device__ __forceinline__ float gf(float x){ float x2=x*x; return x + x2*fmaf(C1G,x2,C0G); }

// ws layout: [0, 10240) uints = 80 rows x 128 ushorts bf16 (Wl | Wat | Was);
// floats [5120, 5129) = K[9] softplus-arg polynomial coeffs.
#define WS_KOFF 5120

// ---------------- k_prep: fold weights + c-poly, once (unchanged) ----------
__global__ __launch_bounds__(256) void k_prep(
    const float* __restrict__ Wl, const float* __restrict__ Wt,
    const float* __restrict__ pw1, const float* __restrict__ pb1,
    const float* __restrict__ pw2, const float* __restrict__ pb2,
    const float* __restrict__ twq, const float* __restrict__ tws,
    const float* __restrict__ twd, float* __restrict__ ws)
{
  const int tid = threadIdx.x;
  ushort* wsU = (ushort*)ws;
  {
    const int j = tid>>4, k0 = (tid&15)*8;
    const float4* src = (const float4*)(Wl + j*128 + k0);
    const float4 b0 = src[0], b1 = src[1];
    uint4 v; v.x=pk2(b0.x,b0.y); v.y=pk2(b0.z,b0.w); v.z=pk2(b1.x,b1.y); v.w=pk2(b1.z,b1.w);
    *(uint4*)(wsU + j*128 + k0) = v;
  }
  {
    const int j = tid>>3, k0 = (tid&7)*16;
    float twa[8], twb[8];
    #pragma unroll
    for (int m=0;m<8;m++){
      const float d = twd[j*8+m];
      twa[m] = twq[j*8+m] + d; twb[m] = tws[j*8+m] - d;
    }
    float oa[16], ob[16];
    #pragma unroll
    for (int i=0;i<16;i++){ oa[i]=0.f; ob[i]=0.f; }
    #pragma unroll
    for (int m=0;m<8;m++){
      const float4* wr = (const float4*)(Wt + m*128 + k0);
      const float ta = twa[m], tbv = twb[m];
      #pragma unroll
      for (int g=0; g<4; ++g){
        const float4 q = wr[g];
        oa[g*4+0]=fmaf(ta,q.x,oa[g*4+0]); ob[g*4+0]=fmaf(tbv,q.x,ob[g*4+0]);
        oa[g*4+1]=fmaf(ta,q.y,oa[g*4+1]); ob[g*4+1]=fmaf(tbv,q.y,ob[g*4+1]);
        oa[g*4+2]=fmaf(ta,q.z,oa[g*4+2]); ob[g*4+2]=fmaf(tbv,q.z,ob[g*4+2]);
        oa[g*4+3]=fmaf(ta,q.w,oa[g*4+3]); ob[g*4+3]=fmaf(tbv,q.w,ob[g*4+3]);
      }
    }
    uint4 v;
    v.x=pk2(oa[0],oa[1]); v.y=pk2(oa[2],oa[3]); v.z=pk2(oa[4],oa[5]); v.w=pk2(oa[6],oa[7]);
    *(uint4*)(wsU + (16+j)*128 + k0) = v;
    v.x=pk2(oa[8],oa[9]); v.y=pk2(oa[10],oa[11]); v.z=pk2(oa[12],oa[13]); v.w=pk2(oa[14],oa[15]);
    *(uint4*)(wsU + (16+j)*128 + k0 + 8) = v;
    v.x=pk2(ob[0],ob[1]); v.y=pk2(ob[2],ob[3]); v.z=pk2(ob[4],ob[5]); v.w=pk2(ob[6],ob[7]);
    *(uint4*)(wsU + (48+j)*128 + k0) = v;
    v.x=pk2(ob[8],ob[9]); v.y=pk2(ob[10],ob[11]); v.z=pk2(ob[12],ob[13]); v.w=pk2(ob[14],ob[15]);
    *(uint4*)(wsU + (48+j)*128 + k0 + 8) = v;
  }
  if (tid < 64){
    const int lj = tid & 31;
    const float kw = (tid < 32) ? (0.5f * pw2[lj]) : 0.f;
    const float bb = pb1[lj], mm = pw1[lj];
    float bp[9], mp[9];
    bp[0]=1.f; mp[0]=1.f;
    #pragma unroll
    for (int i=1;i<9;i++){ bp[i]=bp[i-1]*bb; mp[i]=mp[i-1]*mm; }
    float K[9];
    K[0] = kw*(bb + C0G*bp[2] + C1G*bp[4] + C2G*bp[6] + C3G*bp[8]);
    K[1] = kw*mp[1]*(1.f + 2.f*C0G*bp[1] + 4.f*C1G*bp[3] + 6.f*C2G*bp[5] + 8.f*C3G*bp[7]);
    K[2] = kw*mp[2]*(C0G + 6.f*C1G*bp[2] + 15.f*C2G*bp[4] + 28.f*C3G*bp[6]);
    K[3] = kw*mp[3]*(4.f*C1G*bp[1] + 20.f*C2G*bp[3] + 56.f*C3G*bp[5]);
    K[4] = kw*mp[4]*(C1G + 15.f*C2G*bp[2] + 70.f*C3G*bp[4]);
    K[5] = kw*mp[5]*(6.f*C2G*bp[1] + 56.f*C3G*bp[3]);
    K[6] = kw*mp[6]*(C2G + 28.f*C3G*bp[2]);
    K[7] = kw*mp[7]*(8.f*C3G*bp[1]);
    K[8] = kw*mp[8]*C3G;
    #pragma unroll
    for (int m=1;m<64;m<<=1){
      #pragma unroll
      for (int i=0;i<9;i++) K[i] += __shfl_xor(K[i], m);
    }
    if (tid==0){
      K[0] += pb2[0];
      #pragma unroll
      for (int i=0;i<9;i++) ws[WS_KOFF + i] = K[i];
    }
  }
}

// LDS: exact 64 KiB, no overlays. lp rows are 48B: cols 0..15 l-bf16,
// bytes 32..47 hold row-arrays {h2, l2, alpha/beta} as floats.
#define L_HA  0        // 16384
#define L_HB  16384    // 16384
#define L_UVT 32768    // 13312 (64 x 104 ush, 208B rows)
#define L_UVS 46080    // 13312
#define L_LPT 59392    // 3072 (64 x 48B)
#define L_LPS 62464    // 3072
#define L_TOT 65536

// 512 blocks x 512 thr (8 waves), 2 blocks/CU -> 4 waves/SIMD.
// Wave wv: projection side = wv>>2, strip = wv&3; pair phase: strip + q-half.
__global__ __launch_bounds__(512,4) void k_all(
    const float* __restrict__ h, const float* __restrict__ hsrc,
    const float* __restrict__ tb1, const float* __restrict__ tw2,
    const float* __restrict__ tb2, const float* __restrict__ wsrc,
    float* __restrict__ out)
{
  __shared__ __align__(16) char smem[L_TOT];
  ushort* hA  = (ushort*)(smem + L_HA);
  ushort* hB  = (ushort*)(smem + L_HB);
  ushort* uvT = (ushort*)(smem + L_UVT);
  ushort* uvS = (ushort*)(smem + L_UVS);

  const int tid = threadIdx.x;
  const int L   = blockIdx.x;
  const int blk = ((L & 7) << 6) | (L >> 3);   // XCD-affinity swizzle
  const int bs = (blk & 7)*64;
  const int bt = ((blk>>3)&7)*64;
  const int b  = blk>>6;
  const int lane = tid & 63, wv = tid >> 6;
  const int hi = lane >> 4, c = lane & 15;
  const int sside = wv >> 2, strip = wv & 3, q0 = sside*2;

  // ================= P1: coalesced staging of both tiles ===================
  #pragma unroll
  for (int it=0; it<4; ++it){
    const int i = tid + it*512;
    const int side = i >> 10, i1 = i & 1023;
    const int row = i1 >> 4, cid = i1 & 15;
    const int kk = cid >> 2, h2 = cid & 3;
    const float4* src = (const float4*)((side? hsrc : h)
        + (unsigned)(b*T + (side? bs : bt) + row)*128u + kk*32 + h2*8);
    const float4 a0 = src[0], a1 = src[1];
    uint4 v; v.x=pk2(a0.x,a0.y); v.y=pk2(a0.z,a0.w); v.z=pk2(a1.x,a1.y); v.w=pk2(a1.z,a1.w);
    const int slot = (row>>4)*256 + kk*64 + h2*16 + (row&15);
    *(uint4*)((side? hB : hA) + slot*8) = v;
  }
  float K[9];
  #pragma unroll
  for (int i=0;i<9;i++) K[i] = wsrc[WS_KOFF + i];
  __syncthreads();   // sync1

  // ================= P2: own-side projection (B-frags from L2-hot ws) ======
  const ushort* wbs = (const ushort*)wsrc;
  const ushort* myT = sside ? hB : hA;
  f4v p0={0,0,0,0}, p1={0,0,0,0}, p2={0,0,0,0};
  float nrm = 0.f;
  #pragma unroll
  for (int kk=0;kk<4;kk++){
    union { s8v s; uint4 u; } U;
    U.s = *(const s8v*)(myT + (strip*256 + kk*64 + lane)*8);
    { float x;
      x=bflo(U.u.x); nrm=fmaf(x,x,nrm); x=bfhi(U.u.x); nrm=fmaf(x,x,nrm);
      x=bflo(U.u.y); nrm=fmaf(x,x,nrm); x=bfhi(U.u.y); nrm=fmaf(x,x,nrm);
      x=bflo(U.u.z); nrm=fmaf(x,x,nrm); x=bfhi(U.u.z); nrm=fmaf(x,x,nrm);
      x=bflo(U.u.w); nrm=fmaf(x,x,nrm); x=bfhi(U.u.w); nrm=fmaf(x,x,nrm); }
    const int ko = kk*32 + hi*8;
    const s8v bl = *(const s8v*)(wbs + (c)*128 + ko);
    const s8v b0 = *(const s8v*)(wbs + (16 + 32*sside + c)*128 + ko);
    const s8v b1 = *(const s8v*)(wbs + (32 + 32*sside + c)*128 + ko);
    p0 = MFMA32(U.s, b0, p0,0,0,0);
    p1 = MFMA32(U.s, b1, p1,0,0,0);
    p2 = MFMA32(U.s, bl, p2,0,0,0);
  }
  nrm += __shfl_xor(nrm,16); nrm += __shfl_xor(nrm,32);

  // ================= P3: nonlinears + packs (own side, no barrier needed) ==
  {
    const float t1a = sside ? 0.f : tb1[c];
    const float t1b = sside ? 0.f : tb1[c+16];
    const float w2a = tw2[c], w2b = tw2[c+16];
    const float tb2v = tb2[0];
    ushort* uvMe = sside ? uvS : uvT;
    char* lpBase = smem + (sside ? L_LPS : L_LPT);
    if (hi==0) *(float*)(lpBase + (strip*16 + c)*48 + 32) = nrm;   // h2[row]
    #pragma unroll
    for (int r=0;r<4;r++){
      const int row = strip*16 + hi*4 + r;
      const float a0 = p0[r] + t1a, a1 = p1[r] + t1b;
      const float lv = p2[r];
      float pab = fmaf(w2a, gf(a0), w2b*gf(a1));
      float pl  = lv*lv;
      #pragma unroll
      for (int m=1;m<16;m<<=1){ pab += __shfl_xor(pab,m); pl += __shfl_xor(pl,m); }
      if (c==0){
        float* hb_ = (float*)(lpBase + row*48 + 32);
        hb_[1] = pl;
        hb_[2] = sside ? 0.5f*pab : fmaf(0.5f, pab, tb2v);
      }
      ((ushort*)(lpBase))[row*24 + c] = (ushort)f2bf(lv);
      const float a02=a0*a0, a12=a1*a1;
      if (sside){
        uvMe[row*104 +      c] = (ushort)f2bf(a0);      uvMe[row*104 + 16 + c] = (ushort)f2bf(a1);
        uvMe[row*104 + 32 + c] = (ushort)f2bf(a02);     uvMe[row*104 + 48 + c] = (ushort)f2bf(a12);
        uvMe[row*104 + 64 + c] = (ushort)f2bf(a02*a0);  uvMe[row*104 + 80 + c] = (ushort)f2bf(a12*a1);
      } else {
        const float wa0 = w2a*a0, wa1 = w2b*a1;
        uvMe[row*104 +      c] = (ushort)f2bf(wa0*fmaf(2.f*C1G, a02, C0G));
        uvMe[row*104 + 16 + c] = (ushort)f2bf(wa1*fmaf(2.f*C1G, a12, C0G));
        uvMe[row*104 + 32 + c] = (ushort)f2bf(3.f*C1G*w2a*a02);
        uvMe[row*104 + 48 + c] = (ushort)f2bf(3.f*C1G*w2b*a12);
        uvMe[row*104 + 64 + c] = (ushort)f2bf(2.f*C1G*wa0);
        uvMe[row*104 + 80 + c] = (ushort)f2bf(2.f*C1G*wa1);
      }
    }
  }
  __syncthreads();   // sync2

  // ================= P4: pair MFMAs + epilogue (strip x q-half) ============
  s8v ah[4];
  #pragma unroll
  for (int kk=0;kk<4;kk++) ah[kk] = *(const s8v*)(hA + (strip*256 + kk*64 + lane)*8);
  f4v acch[2], accz[2], accl[2];
  #pragma unroll
  for (int qq=0;qq<2;qq++){ acch[qq]=(f4v){0,0,0,0}; accz[qq]=(f4v){0,0,0,0}; accl[qq]=(f4v){0,0,0,0}; }
  #pragma unroll
  for (int kk=0;kk<4;kk++){
    #pragma unroll
    for (int qq=0;qq<2;qq++)
      acch[qq] = MFMA32(ah[kk], *(const s8v*)(hB + ((q0+qq)*256 + kk*64 + lane)*8), acch[qq],0,0,0);
  }
  #pragma unroll
  for (int ks=0;ks<3;ks++){
    const s8v au = *(const s8v*)(uvT + (strip*16 + c)*104 + ks*32 + hi*8);
    #pragma unroll
    for (int qq=0;qq<2;qq++)
      accz[qq] = MFMA32(au, *(const s8v*)(uvS + ((q0+qq)*16 + c)*104 + ks*32 + hi*8), accz[qq],0,0,0);
  }
  {
    union { uint4 u; s8v s; } Z; Z.u = make_uint4(0,0,0,0);
    const s8v al_ = (hi<2) ? *(const s8v*)(smem + L_LPT + (strip*16+c)*48 + hi*16) : Z.s;
    #pragma unroll
    for (int qq=0;qq<2;qq++){
      const s8v bq = (hi<2) ? *(const s8v*)(smem + L_LPS + ((q0+qq)*16+c)*48 + hi*16) : Z.s;
      accl[qq] = MFMA32(al_, bq, accl[qq],0,0,0);
    }
  }
  float h2t[4], l2t[4], alv[4];
  #pragma unroll
  for (int r=0;r<4;r++){
    const float* th_ = (const float*)(smem + L_LPT + (strip*16 + hi*4 + r)*48 + 32);
    h2t[r]=th_[0]; l2t[r]=th_[1]; alv[r]=th_[2];
  }
  #pragma unroll
  for (int qq=0;qq<2;qq++){
    const int sidx = (q0+qq)*16 + c;
    const float* sh_ = (const float*)(smem + L_LPS + sidx*48 + 32);
    const float h2s=sh_[0], l2s=sh_[1], bet=sh_[2];
    #pragma unroll
    for (int r=0;r<4;r++){
      const float d2 = fmaxf(fmaf(-2.f, acch[qq][r], h2t[r] + h2s), 0.f);
      const float ir = rsqrtf(d2 + EPS2);
      const float l2 = fmaxf(fmaf(-2.f, accl[qq][r], l2t[r] + l2s), 0.f);
      const float lam = fminf(l2, 16.f);
      float zc = K[8];
      #pragma unroll
      for (int i=7;i>=0;i--) zc = fmaf(zc, lam, K[i]);
      const float cc  = __logf(1.f + __expf(zc));         // softplus
      const float phi = __expf(-cc * l2);
      const float z   = accz[qq][r] + alv[r] + bet;
      const float th  = z * fmaf(z*z, -0.33333334f, 1.f); // tanh, |z| small
      out[(unsigned)(b*T + bt + strip*16 + hi*4 + r)*T + bs + sidx] = -th * phi * ir;
    }
  }
}

extern "C" void kernel_launch(void* const* d_in, const int* in_sizes, int n_in,
                              void* d_out, int out_size, void* d_ws, size_t ws_size,
                              hipStream_t stream) {
  const float* h    = (const float*)d_in[0];
  const float* hsrc = (const float*)d_in[1];
  const float* Wl   = (const float*)d_in[2];
  const float* Wt   = (const float*)d_in[3];
  const float* pw1  = (const float*)d_in[4];
  const float* pb1  = (const float*)d_in[5];
  const float* pw2  = (const float*)d_in[6];
  const float* pb2  = (const float*)d_in[7];
  const float* twq  = (const float*)d_in[8];
  const float* tws  = (const float*)d_in[9];
  const float* twd  = (const float*)d_in[10];
  const float* tb1  = (const float*)d_in[11];
  const float* tw2  = (const float*)d_in[12];
  const float* tb2  = (const float*)d_in[13];
  float* ws  = (float*)d_ws;
  float* out = (float*)d_out;

  k_prep<<<dim3(1,1,1),   dim3(256,1,1), 0, stream>>>(Wl,Wt,pw1,pb1,pw2,pb2,twq,tws,twd,ws);
  k_all <<<dim3(512,1,1), dim3(512,1,1), 0, stream>>>(h,hsrc,tb1,tw2,tb2,ws,out);
}

// Round 14
// 22.669 us; speedup vs baseline: 1.1199x; 1.0531x over previous
//
#include <hip/hip_runtime.h>
#include <math.h>

#define T 512
#define EPS2 1e-4f
#define C0G 0.79788456f      // erf(x/sqrt2) = C0 x + C1 x^3 + C2 x^5 + C3 x^7
#define C1G (-0.13298076f)
#define C2G (0.019947114f)
#define C3G (-0.0023746564f)

typedef __attribute__((ext_vector_type(8))) short s8v;   // 8 bf16
typedef __attribute__((ext_vector_type(4))) float f4v;   // MFMA acc

__device__ __forceinline__ uint f2bf(float x){   // f32 -> bf16 bits, RNE
  uint u = __float_as_uint(x);
  return (u + 0x7FFFu + ((u>>16)&1u)) >> 16;
}
__device__ __forceinline__ uint pk2(float a, float b){ return f2bf(a)|(f2bf(b)<<16); }
__device__ __forceinline__ float bflo(uint u){ return __uint_as_float(u<<16); }
__device__ __forceinline__ float bfhi(uint u){ return __uint_as_float(u & 0xFFFF0000u); }
#define MFMA32 __builtin_amdgcn_mfma_f32_16x16x32_bf16
// truncated gelu core (0.5 applied by caller): gf(x) = x + C0 x^2 + C1 x^4
__device__ __forceinline__ float gf(float x){ float x2=x*x; return x + x2*fmaf(C1G,x2,C0G); }

// LDS layout (54528 B). Wb stride 136 ush (272B, 16B-aligned).
// After P2: Wb region -> uvT+lpT+lpS ; hA region -> uvS.
#define L_HA  0        // 16384: t-tile (dead after P2)
#define L_UVS 0        // 13312 (overlays hA)
#define L_HB  16384    // 16384: s-tile (persistent)
#define L_WB  32768    // 21760: 80 x 136 ush (dead after P2)
#define L_UVT 32768    // 13312 (overlays Wb)
#define L_LPT 46080    // 3072: 64 x 48B (cols 0..15 l-bf16; +32: h2,l2,ab floats)
#define L_LPS 49152    // 3072
#define L_TOT 54528

// Single dispatch: 512 blocks x 512 thr (8 waves), 2 blocks/CU -> 4 waves/SIMD.
// Per block: fold weights -> stage tiles -> project own side -> nonlinears ->
// pair MFMAs -> epilogue. 3 barriers. No ws, no second kernel, no fences.
__global__ __launch_bounds__(512,4) void k_all(
    const float* __restrict__ h, const float* __restrict__ hsrc,
    const float* __restrict__ Wl, const float* __restrict__ Wt,
    const float* __restrict__ pw1, const float* __restrict__ pb1,
    const float* __restrict__ pw2, const float* __restrict__ pb2,
    const float* __restrict__ twq, const float* __restrict__ tws,
    const float* __restrict__ twd, const float* __restrict__ tb1,
    const float* __restrict__ tw2, const float* __restrict__ tb2,
    float* __restrict__ out)
{
  __shared__ __align__(16) char smem[L_TOT];
  ushort* hA  = (ushort*)(smem + L_HA);
  ushort* hB  = (ushort*)(smem + L_HB);
  ushort* Wb  = (ushort*)(smem + L_WB);
  ushort* uvT = (ushort*)(smem + L_UVT);
  ushort* uvS = (ushort*)(smem + L_UVS);

  const int tid = threadIdx.x;
  const int Lb  = blockIdx.x;
  const int blk = ((Lb & 7) << 6) | (Lb >> 3);   // XCD-affinity swizzle
  const int bs = (blk & 7)*64;
  const int bt = ((blk>>3)&7)*64;
  const int b  = blk>>6;
  const int lane = tid & 63, wv = tid >> 6;
  const int hi = lane >> 4, c = lane & 15;
  const int sside = wv >> 2, strip = wv & 3, q0 = sside*2;

  // ================= P0a: coalesced staging of both tiles ==================
  #pragma unroll
  for (int it=0; it<4; ++it){
    const int i = tid + it*512;
    const int side = i >> 10, i1 = i & 1023;
    const int row = i1 >> 4, cid = i1 & 15;
    const int kk = cid >> 2, h2 = cid & 3;
    const float4* src = (const float4*)((side? hsrc : h)
        + (unsigned)(b*T + (side? bs : bt) + row)*128u + kk*32 + h2*8);
    const float4 a0 = src[0], a1 = src[1];
    uint4 v; v.x=pk2(a0.x,a0.y); v.y=pk2(a0.z,a0.w); v.z=pk2(a1.x,a1.y); v.w=pk2(a1.z,a1.w);
    const int slot = (row>>4)*256 + kk*64 + h2*16 + (row&15);
    *(uint4*)((side? hB : hA) + slot*8) = v;
  }
  // ================= P0b: Wl pack + fold into LDS Wb =======================
  if (tid < 256){
    const int j = tid>>4, k0 = (tid&15)*8;
    const float4* src = (const float4*)(Wl + j*128 + k0);
    const float4 b0 = src[0], b1 = src[1];
    uint4 v; v.x=pk2(b0.x,b0.y); v.y=pk2(b0.z,b0.w); v.z=pk2(b1.x,b1.y); v.w=pk2(b1.z,b1.w);
    *(uint4*)(Wb + j*136 + k0) = v;
  }
  {
    const int sideF = tid>>8, j=(tid>>3)&31, k0=(tid&7)*16;
    float tw[8];
    #pragma unroll
    for (int m=0;m<8;m++){
      const float d = twd[j*8+m];
      tw[m] = sideF ? (tws[j*8+m]-d) : (twq[j*8+m]+d);
    }
    float o[16];
    #pragma unroll
    for (int i=0;i<16;i++) o[i]=0.f;
    #pragma unroll
    for (int m=0;m<8;m++){
      const float4* wr = (const float4*)(Wt + m*128 + k0);
      #pragma unroll
      for (int g=0; g<4; ++g){
        const float4 qv = wr[g];
        o[g*4+0]=fmaf(tw[m],qv.x,o[g*4+0]); o[g*4+1]=fmaf(tw[m],qv.y,o[g*4+1]);
        o[g*4+2]=fmaf(tw[m],qv.z,o[g*4+2]); o[g*4+3]=fmaf(tw[m],qv.w,o[g*4+3]);
      }
    }
    ushort* dst = Wb + (16 + sideF*32 + j)*136 + k0;
    uint4 v;
    v.x=pk2(o[0],o[1]); v.y=pk2(o[2],o[3]); v.z=pk2(o[4],o[5]); v.w=pk2(o[6],o[7]);
    *(uint4*)dst = v;
    v.x=pk2(o[8],o[9]); v.y=pk2(o[10],o[11]); v.z=pk2(o[12],o[13]); v.w=pk2(o[14],o[15]);
    *(uint4*)(dst+8) = v;
  }
  // ================= P0c: K[9] softplus-arg poly (per-wave) ================
  float K[9];
  {
    const int lj = lane & 31;
    const float kw = (lane < 32) ? (0.5f * pw2[lj]) : 0.f;
    const float bb = pb1[lj], mm = pw1[lj];
    float bp[9], mp[9];
    bp[0]=1.f; mp[0]=1.f;
    #pragma unroll
    for (int i=1;i<9;i++){ bp[i]=bp[i-1]*bb; mp[i]=mp[i-1]*mm; }
    K[0] = kw*(bb + C0G*bp[2] + C1G*bp[4] + C2G*bp[6] + C3G*bp[8]);
    K[1] = kw*mp[1]*(1.f + 2.f*C0G*bp[1] + 4.f*C1G*bp[3] + 6.f*C2G*bp[5] + 8.f*C3G*bp[7]);
    K[2] = kw*mp[2]*(C0G + 6.f*C1G*bp[2] + 15.f*C2G*bp[4] + 28.f*C3G*bp[6]);
    K[3] = kw*mp[3]*(4.f*C1G*bp[1] + 20.f*C2G*bp[3] + 56.f*C3G*bp[5]);
    K[4] = kw*mp[4]*(C1G + 15.f*C2G*bp[2] + 70.f*C3G*bp[4]);
    K[5] = kw*mp[5]*(6.f*C2G*bp[1] + 56.f*C3G*bp[3]);
    K[6] = kw*mp[6]*(C2G + 28.f*C3G*bp[2]);
    K[7] = kw*mp[7]*(8.f*C3G*bp[1]);
    K[8] = kw*mp[8]*C3G;
    #pragma unroll
    for (int m=1;m<64;m<<=1){
      #pragma unroll
      for (int i=0;i<9;i++) K[i] += __shfl_xor(K[i], m);
    }
    K[0] += pb2[0];
  }
  __syncthreads();   // sync1: tiles + Wb ready

  // ================= P2: own-side projection (B-frags from LDS Wb) =========
  const ushort* myT = sside ? hB : hA;
  f4v p0={0,0,0,0}, p1={0,0,0,0}, p2={0,0,0,0};
  float nrm = 0.f;
  #pragma unroll
  for (int kk=0;kk<4;kk++){
    union { s8v s; uint4 u; } U;
    U.s = *(const s8v*)(myT + (strip*256 + kk*64 + lane)*8);
    { float x;
      x=bflo(U.u.x); nrm=fmaf(x,x,nrm); x=bfhi(U.u.x); nrm=fmaf(x,x,nrm);
      x=bflo(U.u.y); nrm=fmaf(x,x,nrm); x=bfhi(U.u.y); nrm=fmaf(x,x,nrm);
      x=bflo(U.u.z); nrm=fmaf(x,x,nrm); x=bfhi(U.u.z); nrm=fmaf(x,x,nrm);
      x=bflo(U.u.w); nrm=fmaf(x,x,nrm); x=bfhi(U.u.w); nrm=fmaf(x,x,nrm); }
    const int ko = kk*32 + hi*8;
    const s8v bl = *(const s8v*)(Wb + (c)*136 + ko);
    const s8v b0 = *(const s8v*)(Wb + (16 + 32*sside + c)*136 + ko);
    const s8v b1 = *(const s8v*)(Wb + (32 + 32*sside + c)*136 + ko);
    p0 = MFMA32(U.s, b0, p0,0,0,0);
    p1 = MFMA32(U.s, b1, p1,0,0,0);
    p2 = MFMA32(U.s, bl, p2,0,0,0);
  }
  nrm += __shfl_xor(nrm,16); nrm += __shfl_xor(nrm,32);
  // t-side pair A-fragments to regs before hA is overlaid
  s8v ah[4];
  #pragma unroll
  for (int kk=0;kk<4;kk++) ah[kk] = *(const s8v*)(hA + (strip*256 + kk*64 + lane)*8);
  __syncthreads();   // sync_mid: Wb/hA dead -> overlays safe

  // ================= P3: nonlinears + packs (own side) =====================
  {
    const float t1a = sside ? 0.f : tb1[c];
    const float t1b = sside ? 0.f : tb1[c+16];
    const float w2a = tw2[c], w2b = tw2[c+16];
    const float tb2v = tb2[0];
    ushort* uvMe = sside ? uvS : uvT;
    char* lpBase = smem + (sside ? L_LPS : L_LPT);
    if (hi==0) *(float*)(lpBase + (strip*16 + c)*48 + 32) = nrm;   // h2[row]
    #pragma unroll
    for (int r=0;r<4;r++){
      const int row = strip*16 + hi*4 + r;
      const float a0 = p0[r] + t1a, a1 = p1[r] + t1b;
      const float lv = p2[r];
      float pab = fmaf(w2a, gf(a0), w2b*gf(a1));
      float pl  = lv*lv;
      #pragma unroll
      for (int m=1;m<16;m<<=1){ pab += __shfl_xor(pab,m); pl += __shfl_xor(pl,m); }
      if (c==0){
        float* hb_ = (float*)(lpBase + row*48 + 32);
        hb_[1] = pl;
        hb_[2] = sside ? 0.5f*pab : fmaf(0.5f, pab, tb2v);
      }
      ((ushort*)(lpBase))[row*24 + c] = (ushort)f2bf(lv);
      const float a02=a0*a0, a12=a1*a1;
      if (sside){
        uvMe[row*104 +      c] = (ushort)f2bf(a0);      uvMe[row*104 + 16 + c] = (ushort)f2bf(a1);
        uvMe[row*104 + 32 + c] = (ushort)f2bf(a02);     uvMe[row*104 + 48 + c] = (ushort)f2bf(a12);
        uvMe[row*104 + 64 + c] = (ushort)f2bf(a02*a0);  uvMe[row*104 + 80 + c] = (ushort)f2bf(a12*a1);
      } else {
        const float wa0 = w2a*a0, wa1 = w2b*a1;
        uvMe[row*104 +      c] = (ushort)f2bf(wa0*fmaf(2.f*C1G, a02, C0G));
        uvMe[row*104 + 16 + c] = (ushort)f2bf(wa1*fmaf(2.f*C1G, a12, C0G));
        uvMe[row*104 + 32 + c] = (ushort)f2bf(3.f*C1G*w2a*a02);
        uvMe[row*104 + 48 + c] = (ushort)f2bf(3.f*C1G*w2b*a12);
        uvMe[row*104 + 64 + c] = (ushort)f2bf(2.f*C1G*wa0);
        uvMe[row*104 + 80 + c] = (ushort)f2bf(2.f*C1G*wa1);
      }
    }
  }
  __syncthreads();   // sync2

  // ================= P4: pair MFMAs + epilogue (strip x q-half) ============
  f4v acch[2], accz[2], accl[2];
  #pragma unroll
  for (int qq=0;qq<2;qq++){ acch[qq]=(f4v){0,0,0,0}; accz[qq]=(f4v){0,0,0,0}; accl[qq]=(f4v){0,0,0,0}; }
  #pragma unroll
  for (int kk=0;kk<4;kk++){
    #pragma unroll
    for (int qq=0;qq<2;qq++)
      acch[qq] = MFMA32(ah[kk], *(const s8v*)(hB + ((q0+qq)*256 + kk*64 + lane)*8), acch[qq],0,0,0);
  }
  #pragma unroll
  for (int ks=0;ks<3;ks++){
    const s8v au = *(const s8v*)(uvT + (strip*16 + c)*104 + ks*32 + hi*8);
    #pragma unroll
    for (int qq=0;qq<2;qq++)
      accz[qq] = MFMA32(au, *(const s8v*)(uvS + ((q0+qq)*16 + c)*104 + ks*32 + hi*8), accz[qq],0,0,0);
  }
  {
    union { uint4 u; s8v s; } Z; Z.u = make_uint4(0,0,0,0);
    const s8v al_ = (hi<2) ? *(const s8v*)(smem + L_LPT + (strip*16+c)*48 + hi*16) : Z.s;
    #pragma unroll
    for (int qq=0;qq<2;qq++){
      const s8v bq = (hi<2) ? *(const s8v*)(smem + L_LPS + ((q0+qq)*16+c)*48 + hi*16) : Z.s;
      accl[qq] = MFMA32(al_, bq, accl[qq],0,0,0);
    }
  }
  float h2t[4], l2t[4], alv[4];
  #pragma unroll
  for (int r=0;r<4;r++){
    const float* th_ = (const float*)(smem + L_LPT + (strip*16 + hi*4 + r)*48 + 32);
    h2t[r]=th_[0]; l2t[r]=th_[1]; alv[r]=th_[2];
  }
  #pragma unroll
  for (int qq=0;qq<2;qq++){
    const int sidx = (q0+qq)*16 + c;
    const float* sh_ = (const float*)(smem + L_LPS + sidx*48 + 32);
    const float h2s=sh_[0], l2s=sh_[1], bet=sh_[2];
    #pragma unroll
    for (int r=0;r<4;r++){
      const float d2 = fmaxf(fmaf(-2.f, acch[qq][r], h2t[r] + h2s), 0.f);
      const float ir = rsqrtf(d2 + EPS2);
      const float l2 = fmaxf(fmaf(-2.f, accl[qq][r], l2t[r] + l2s), 0.f);
      const float lam = fminf(l2, 16.f);
      float zc = K[8];
      #pragma unroll
      for (int i=7;i>=0;i--) zc = fmaf(zc, lam, K[i]);
      const float cc  = __logf(1.f + __expf(zc));         // softplus
      const float phi = __expf(-cc * l2);
      const float z   = accz[qq][r] + alv[r] + bet;
      const float th  = z * fmaf(z*z, -0.33333334f, 1.f); // tanh, |z| small
      __builtin_nontemporal_store(-th * phi * ir,
        out + (unsigned)(b*T + bt + strip*16 + hi*4 + r)*T + bs + sidx);
    }
  }
}

extern "C" void kernel_launch(void* const* d_in, const int* in_sizes, int n_in,
                              void* d_out, int out_size, void* d_ws, size_t ws_size,
                              hipStream_t stream) {
  const float* h    = (const float*)d_in[0];
  const float* hsrc = (const float*)d_in[1];
  const float* Wl   = (const float*)d_in[2];
  const float* Wt   = (const float*)d_in[3];
  const float* pw1  = (const float*)d_in[4];
  const float* pb1  = (const float*)d_in[5];
  const float* pw2  = (const float*)d_in[6];
  const float* pb2  = (const float*)d_in[7];
  const float* twq  = (const float*)d_in[8];
  const float* tws  = (const float*)d_in[9];
  const float* twd  = (const float*)d_in[10];
  const float* tb1  = (const float*)d_in[11];
  const float* tw2  = (const float*)d_in[12];
  const float* tb2  = (const float*)d_in[13];
  float* out = (float*)d_out;

  k_all<<<dim3(512,1,1), dim3(512,1,1), 0, stream>>>(
      h,hsrc,Wl,Wt,pw1,pb1,pw2,pb2,twq,tws,twd,tb1,tw2,tb2,out);
}

// Round 15
// 20.793 us; speedup vs baseline: 1.2210x; 1.0903x over previous
//
#include <hip/hip_runtime.h>
#include <math.h>

#define T 512
#define EPS2 1e-4f
#define C0G 0.79788456f      // erf(x/sqrt2) = C0 x + C1 x^3 + C2 x^5 + C3 x^7
#define C1G (-0.13298076f)
#define C2G (0.019947114f)
#define C3G (-0.0023746564f)

typedef __attribute__((ext_vector_type(8))) short s8v;   // 8 bf16
typedef __attribute__((ext_vector_type(4))) float f4v;   // MFMA acc

__device__ __forceinline__ uint f2bf(float x){   // f32 -> bf16 bits, RNE
  uint u = __float_as_uint(x);
  return (u + 0x7FFFu + ((u>>16)&1u)) >> 16;
}
__device__ __forceinline__ uint pk2(float a, float b){ return f2bf(a)|(f2bf(b)<<16); }
__device__ __forceinline__ float bflo(uint u){ return __uint_as_float(u<<16); }
__device__ __forceinline__ float bfhi(uint u){ return __uint_as_float(u & 0xFFFF0000u); }
#define MFMA32 __builtin_amdgcn_mfma_f32_16x16x32_bf16
// truncated gelu core (0.5 applied by caller): gf(x) = x + C0 x^2 + C1 x^4
__device__ __forceinline__ float gf(float x){ float x2=x*x; return x + x2*fmaf(C1G,x2,C0G); }

// LDS layout (74048 B, 2 blocks/CU = 148 KB < 160).
// Wb stays LIVE the whole kernel (needed for iter-1 s-projection).
// hA dead after P2a -> uvS overlays it.
#define L_HA   0        // 16384: t-tile
#define L_UVS  0        // 13312 (overlays hA)
#define L_HB   16384    // 16384: s-tile (restaged for iter 1)
#define L_WB   32768    // 21760: 80 x 136 ush (live)
#define L_UVT  54528    // 13312
#define L_LPT  67840    // 3072: 64 x 48B (cols 0..15 l-bf16; +32: h2,l2,ab floats)
#define L_LPS  70912    // 3072
#define L_K    73984    // 64: K[9]
#define L_TOT  74048

// 256 WGs x 512 thr (8 waves), 2 blocks/CU -> 4 waves/SIMD.
// Block = (b, bt, bs0): one 64-row t-strip x 128 s-cols (two 64x64 tiles).
// t-side staging/projection/fold/K done ONCE; s-side done per tile.
__global__ __launch_bounds__(512,4) void k_all(
    const float* __restrict__ h, const float* __restrict__ hsrc,
    const float* __restrict__ Wl, const float* __restrict__ Wt,
    const float* __restrict__ pw1, const float* __restrict__ pb1,
    const float* __restrict__ pw2, const float* __restrict__ pb2,
    const float* __restrict__ twq, const float* __restrict__ tws,
    const float* __restrict__ twd, const float* __restrict__ tb1,
    const float* __restrict__ tw2, const float* __restrict__ tb2,
    float* __restrict__ out)
{
  __shared__ __align__(16) char smem[L_TOT];
  ushort* hA  = (ushort*)(smem + L_HA);
  ushort* hB  = (ushort*)(smem + L_HB);
  ushort* Wb  = (ushort*)(smem + L_WB);
  ushort* uvT = (ushort*)(smem + L_UVT);
  ushort* uvS = (ushort*)(smem + L_UVS);

  const int tid = threadIdx.x;
  const int Lb  = blockIdx.x;
  const int blk = ((Lb & 7) << 5) | (Lb >> 3);   // XCD-affinity swizzle (256 WGs)
  const int b   = blk >> 5;
  const int bt  = ((blk >> 2) & 7) * 64;
  const int bs0 = (blk & 3) * 128;
  const int lane = tid & 63, wv = tid >> 6;
  const int hi = lane >> 4, c = lane & 15;
  const int sside = wv >> 2, strip = wv & 3, q0 = sside*2;

  // ================= P0a: coalesced staging, t-tile + s-tile 0 =============
  #pragma unroll
  for (int it=0; it<2; ++it){          // t-tile
    const int i = tid + it*512;
    const int row = i >> 4, cid = i & 15;
    const int kk = cid >> 2, h2 = cid & 3;
    const float4* src = (const float4*)(h + (unsigned)(b*T + bt + row)*128u + kk*32 + h2*8);
    const float4 a0 = src[0], a1 = src[1];
    uint4 v; v.x=pk2(a0.x,a0.y); v.y=pk2(a0.z,a0.w); v.z=pk2(a1.x,a1.y); v.w=pk2(a1.z,a1.w);
    *(uint4*)(hA + ((row>>4)*256 + kk*64 + h2*16 + (row&15))*8) = v;
  }
  #pragma unroll
  for (int it=0; it<2; ++it){          // s-tile 0
    const int i = tid + it*512;
    const int row = i >> 4, cid = i & 15;
    const int kk = cid >> 2, h2 = cid & 3;
    const float4* src = (const float4*)(hsrc + (unsigned)(b*T + bs0 + row)*128u + kk*32 + h2*8);
    const float4 a0 = src[0], a1 = src[1];
    uint4 v; v.x=pk2(a0.x,a0.y); v.y=pk2(a0.z,a0.w); v.z=pk2(a1.x,a1.y); v.w=pk2(a1.z,a1.w);
    *(uint4*)(hB + ((row>>4)*256 + kk*64 + h2*16 + (row&15))*8) = v;
  }
  // ================= P0b: Wl pack + fold into LDS Wb =======================
  if (tid < 256){
    const int j = tid>>4, k0 = (tid&15)*8;
    const float4* src = (const float4*)(Wl + j*128 + k0);
    const float4 b0 = src[0], b1 = src[1];
    uint4 v; v.x=pk2(b0.x,b0.y); v.y=pk2(b0.z,b0.w); v.z=pk2(b1.x,b1.y); v.w=pk2(b1.z,b1.w);
    *(uint4*)(Wb + j*136 + k0) = v;
  }
  {
    const int sideF = tid>>8, j=(tid>>3)&31, k0=(tid&7)*16;
    float tw[8];
    #pragma unroll
    for (int m=0;m<8;m++){
      const float d = twd[j*8+m];
      tw[m] = sideF ? (tws[j*8+m]-d) : (twq[j*8+m]+d);
    }
    float o[16];
    #pragma unroll
    for (int i=0;i<16;i++) o[i]=0.f;
    #pragma unroll
    for (int m=0;m<8;m++){
      const float4* wr = (const float4*)(Wt + m*128 + k0);
      #pragma unroll
      for (int g=0; g<4; ++g){
        const float4 qv = wr[g];
        o[g*4+0]=fmaf(tw[m],qv.x,o[g*4+0]); o[g*4+1]=fmaf(tw[m],qv.y,o[g*4+1]);
        o[g*4+2]=fmaf(tw[m],qv.z,o[g*4+2]); o[g*4+3]=fmaf(tw[m],qv.w,o[g*4+3]);
      }
    }
    ushort* dst = Wb + (16 + sideF*32 + j)*136 + k0;
    uint4 v;
    v.x=pk2(o[0],o[1]); v.y=pk2(o[2],o[3]); v.z=pk2(o[4],o[5]); v.w=pk2(o[6],o[7]);
    *(uint4*)dst = v;
    v.x=pk2(o[8],o[9]); v.y=pk2(o[10],o[11]); v.z=pk2(o[12],o[13]); v.w=pk2(o[14],o[15]);
    *(uint4*)(dst+8) = v;
  }
  // ================= P0c: K[9] (wave 0 only -> LDS) ========================
  if (wv == 0){
    const int lj = lane & 31;
    const float kw = (lane < 32) ? (0.5f * pw2[lj]) : 0.f;
    const float bb = pb1[lj], mm = pw1[lj];
    float bp[9], mp[9];
    bp[0]=1.f; mp[0]=1.f;
    #pragma unroll
    for (int i=1;i<9;i++){ bp[i]=bp[i-1]*bb; mp[i]=mp[i-1]*mm; }
    float Kq[9];
    Kq[0] = kw*(bb + C0G*bp[2] + C1G*bp[4] + C2G*bp[6] + C3G*bp[8]);
    Kq[1] = kw*mp[1]*(1.f + 2.f*C0G*bp[1] + 4.f*C1G*bp[3] + 6.f*C2G*bp[5] + 8.f*C3G*bp[7]);
    Kq[2] = kw*mp[2]*(C0G + 6.f*C1G*bp[2] + 15.f*C2G*bp[4] + 28.f*C3G*bp[6]);
    Kq[3] = kw*mp[3]*(4.f*C1G*bp[1] + 20.f*C2G*bp[3] + 56.f*C3G*bp[5]);
    Kq[4] = kw*mp[4]*(C1G + 15.f*C2G*bp[2] + 70.f*C3G*bp[4]);
    Kq[5] = kw*mp[5]*(6.f*C2G*bp[1] + 56.f*C3G*bp[3]);
    Kq[6] = kw*mp[6]*(C2G + 28.f*C3G*bp[2]);
    Kq[7] = kw*mp[7]*(8.f*C3G*bp[1]);
    Kq[8] = kw*mp[8]*C3G;
    #pragma unroll
    for (int m=1;m<64;m<<=1){
      #pragma unroll
      for (int i=0;i<9;i++) Kq[i] += __shfl_xor(Kq[i], m);
    }
    if (lane==0){
      Kq[0] += pb2[0];
      #pragma unroll
      for (int i=0;i<9;i++) ((float*)(smem+L_K))[i] = Kq[i];
    }
  }
  __syncthreads();   // sync1

  // ================= P2a: own-side projection + ah preload =================
  const ushort* myT = sside ? hB : hA;
  f4v p0={0,0,0,0}, p1={0,0,0,0}, p2={0,0,0,0};
  float nrm = 0.f;
  #pragma unroll
  for (int kk=0;kk<4;kk++){
    union { s8v s; uint4 u; } U;
    U.s = *(const s8v*)(myT + (strip*256 + kk*64 + lane)*8);
    { float x;
      x=bflo(U.u.x); nrm=fmaf(x,x,nrm); x=bfhi(U.u.x); nrm=fmaf(x,x,nrm);
      x=bflo(U.u.y); nrm=fmaf(x,x,nrm); x=bfhi(U.u.y); nrm=fmaf(x,x,nrm);
      x=bflo(U.u.z); nrm=fmaf(x,x,nrm); x=bfhi(U.u.z); nrm=fmaf(x,x,nrm);
      x=bflo(U.u.w); nrm=fmaf(x,x,nrm); x=bfhi(U.u.w); nrm=fmaf(x,x,nrm); }
    const int ko = kk*32 + hi*8;
    const s8v bl = *(const s8v*)(Wb + (c)*136 + ko);
    const s8v b0 = *(const s8v*)(Wb + (16 + 32*sside + c)*136 + ko);
    const s8v b1 = *(const s8v*)(Wb + (32 + 32*sside + c)*136 + ko);
    p0 = MFMA32(U.s, b0, p0,0,0,0);
    p1 = MFMA32(U.s, b1, p1,0,0,0);
    p2 = MFMA32(U.s, bl, p2,0,0,0);
  }
  nrm += __shfl_xor(nrm,16); nrm += __shfl_xor(nrm,32);
  s8v ah[4];
  #pragma unroll
  for (int kk=0;kk<4;kk++) ah[kk] = *(const s8v*)(hA + (strip*256 + kk*64 + lane)*8);
  __syncthreads();   // sync_mid: hA dead -> uvS region safe

  // ================= P3a: nonlinears + packs (own side) ====================
  const float w2a = tw2[c], w2b = tw2[c+16];
  const float tb2v = tb2[0];
  {
    const float t1a = sside ? 0.f : tb1[c];
    const float t1b = sside ? 0.f : tb1[c+16];
    ushort* uvMe = sside ? uvS : uvT;
    char* lpBase = smem + (sside ? L_LPS : L_LPT);
    if (hi==0) *(float*)(lpBase + (strip*16 + c)*48 + 32) = nrm;
    #pragma unroll
    for (int r=0;r<4;r++){
      const int row = strip*16 + hi*4 + r;
      const float a0 = p0[r] + t1a, a1 = p1[r] + t1b;
      const float lv = p2[r];
      float pab = fmaf(w2a, gf(a0), w2b*gf(a1));
      float pl  = lv*lv;
      #pragma unroll
      for (int m=1;m<16;m<<=1){ pab += __shfl_xor(pab,m); pl += __shfl_xor(pl,m); }
      if (c==0){
        float* hb_ = (float*)(lpBase + row*48 + 32);
        hb_[1] = pl;
        hb_[2] = sside ? 0.5f*pab : fmaf(0.5f, pab, tb2v);
      }
      ((ushort*)(lpBase))[row*24 + c] = (ushort)f2bf(lv);
      const float a02=a0*a0, a12=a1*a1;
      if (sside){
        uvMe[row*104 +      c] = (ushort)f2bf(a0);      uvMe[row*104 + 16 + c] = (ushort)f2bf(a1);
        uvMe[row*104 + 32 + c] = (ushort)f2bf(a02);     uvMe[row*104 + 48 + c] = (ushort)f2bf(a12);
        uvMe[row*104 + 64 + c] = (ushort)f2bf(a02*a0);  uvMe[row*104 + 80 + c] = (ushort)f2bf(a12*a1);
      } else {
        const float wa0 = w2a*a0, wa1 = w2b*a1;
        uvMe[row*104 +      c] = (ushort)f2bf(wa0*fmaf(2.f*C1G, a02, C0G));
        uvMe[row*104 + 16 + c] = (ushort)f2bf(wa1*fmaf(2.f*C1G, a12, C0G));
        uvMe[row*104 + 32 + c] = (ushort)f2bf(3.f*C1G*w2a*a02);
        uvMe[row*104 + 48 + c] = (ushort)f2bf(3.f*C1G*w2b*a12);
        uvMe[row*104 + 64 + c] = (ushort)f2bf(2.f*C1G*wa0);
        uvMe[row*104 + 80 + c] = (ushort)f2bf(2.f*C1G*wa1);
      }
    }
  }
  __syncthreads();   // sync2

  float K[9];
  #pragma unroll
  for (int i=0;i<9;i++) K[i] = ((const float*)(smem+L_K))[i];

  // ================= P4 macro body (per s-tile) ============================
  #define PAIR_PHASE(BS)                                                        \
  {                                                                             \
    f4v acch[2], accz[2], accl[2];                                              \
    _Pragma("unroll")                                                           \
    for (int qq=0;qq<2;qq++){ acch[qq]=(f4v){0,0,0,0}; accz[qq]=(f4v){0,0,0,0}; accl[qq]=(f4v){0,0,0,0}; } \
    _Pragma("unroll")                                                           \
    for (int kk=0;kk<4;kk++){                                                   \
      _Pragma("unroll")                                                         \
      for (int qq=0;qq<2;qq++)                                                  \
        acch[qq] = MFMA32(ah[kk], *(const s8v*)(hB + ((q0+qq)*256 + kk*64 + lane)*8), acch[qq],0,0,0); \
    }                                                                           \
    _Pragma("unroll")                                                           \
    for (int ks=0;ks<3;ks++){                                                   \
      const s8v au = *(const s8v*)(uvT + (strip*16 + c)*104 + ks*32 + hi*8);    \
      _Pragma("unroll")                                                         \
      for (int qq=0;qq<2;qq++)                                                  \
        accz[qq] = MFMA32(au, *(const s8v*)(uvS + ((q0+qq)*16 + c)*104 + ks*32 + hi*8), accz[qq],0,0,0); \
    }                                                                           \
    {                                                                           \
      union { uint4 u; s8v s; } Z; Z.u = make_uint4(0,0,0,0);                   \
      const s8v al_ = (hi<2) ? *(const s8v*)(smem + L_LPT + (strip*16+c)*48 + hi*16) : Z.s; \
      _Pragma("unroll")                                                         \
      for (int qq=0;qq<2;qq++){                                                 \
        const s8v bq = (hi<2) ? *(const s8v*)(smem + L_LPS + ((q0+qq)*16+c)*48 + hi*16) : Z.s; \
        accl[qq] = MFMA32(al_, bq, accl[qq],0,0,0);                             \
      }                                                                         \
    }                                                                           \
    float h2t[4], l2t[4], alv[4];                                               \
    _Pragma("unroll")                                                           \
    for (int r=0;r<4;r++){                                                      \
      const float* th_ = (const float*)(smem + L_LPT + (strip*16 + hi*4 + r)*48 + 32); \
      h2t[r]=th_[0]; l2t[r]=th_[1]; alv[r]=th_[2];                              \
    }                                                                           \
    _Pragma("unroll")                                                           \
    for (int qq=0;qq<2;qq++){                                                   \
      const int sidx = (q0+qq)*16 + c;                                          \
      const float* sh_ = (const float*)(smem + L_LPS + sidx*48 + 32);           \
      const float h2s=sh_[0], l2s=sh_[1], bet=sh_[2];                           \
      _Pragma("unroll")                                                         \
      for (int r=0;r<4;r++){                                                    \
        const float d2 = fmaxf(fmaf(-2.f, acch[qq][r], h2t[r] + h2s), 0.f);     \
        const float ir = rsqrtf(d2 + EPS2);                                     \
        const float l2 = fmaxf(fmaf(-2.f, accl[qq][r], l2t[r] + l2s), 0.f);     \
        const float lam = fminf(l2, 16.f);                                      \
        float zc = K[8];                                                        \
        _Pragma("unroll")                                                       \
        for (int i=7;i>=0;i--) zc = fmaf(zc, lam, K[i]);                        \
        const float cc  = __logf(1.f + __expf(zc));                             \
        const float phi = __expf(-cc * l2);                                     \
        const float z   = accz[qq][r] + alv[r] + bet;                           \
        const float th  = z * fmaf(z*z, -0.33333334f, 1.f);                     \
        __builtin_nontemporal_store(-th * phi * ir,                             \
          out + (unsigned)(b*T + bt + strip*16 + hi*4 + r)*T + (BS) + sidx);    \
      }                                                                         \
    }                                                                           \
  }

  // ================= tile 0 ================================================
  PAIR_PHASE(bs0)

  // ================= tile 1: restage s-side, reproject, pack, pair =========
  __syncthreads();   // sync3: hB/uvS/lpS reads of tile 0 complete
  #pragma unroll
  for (int it=0; it<2; ++it){
    const int i = tid + it*512;
    const int row = i >> 4, cid = i & 15;
    const int kk = cid >> 2, h2 = cid & 3;
    const float4* src = (const float4*)(hsrc + (unsigned)(b*T + bs0 + 64 + row)*128u + kk*32 + h2*8);
    const float4 a0 = src[0], a1 = src[1];
    uint4 v; v.x=pk2(a0.x,a0.y); v.y=pk2(a0.z,a0.w); v.z=pk2(a1.x,a1.y); v.w=pk2(a1.z,a1.w);
    *(uint4*)(hB + ((row>>4)*256 + kk*64 + h2*16 + (row&15))*8) = v;
  }
  __syncthreads();   // sync4: hB(tile1) ready
  if (sside == 1){
    f4v q0v={0,0,0,0}, q1v={0,0,0,0}, q2v={0,0,0,0};
    float nr2 = 0.f;
    #pragma unroll
    for (int kk=0;kk<4;kk++){
      union { s8v s; uint4 u; } U;
      U.s = *(const s8v*)(hB + (strip*256 + kk*64 + lane)*8);
      { float x;
        x=bflo(U.u.x); nr2=fmaf(x,x,nr2); x=bfhi(U.u.x); nr2=fmaf(x,x,nr2);
        x=bflo(U.u.y); nr2=fmaf(x,x,nr2); x=bfhi(U.u.y); nr2=fmaf(x,x,nr2);
        x=bflo(U.u.z); nr2=fmaf(x,x,nr2); x=bfhi(U.u.z); nr2=fmaf(x,x,nr2);
        x=bflo(U.u.w); nr2=fmaf(x,x,nr2); x=bfhi(U.u.w); nr2=fmaf(x,x,nr2); }
      const int ko = kk*32 + hi*8;
      const s8v bl = *(const s8v*)(Wb + (c)*136 + ko);
      const s8v b0 = *(const s8v*)(Wb + (48 + c)*136 + ko);
      const s8v b1 = *(const s8v*)(Wb + (64 + c)*136 + ko);
      q0v = MFMA32(U.s, b0, q0v,0,0,0);
      q1v = MFMA32(U.s, b1, q1v,0,0,0);
      q2v = MFMA32(U.s, bl, q2v,0,0,0);
    }
    nr2 += __shfl_xor(nr2,16); nr2 += __shfl_xor(nr2,32);
    char* lpBase = smem + L_LPS;
    if (hi==0) *(float*)(lpBase + (strip*16 + c)*48 + 32) = nr2;
    #pragma unroll
    for (int r=0;r<4;r++){
      const int row = strip*16 + hi*4 + r;
      const float a0 = q0v[r], a1 = q1v[r];
      const float lv = q2v[r];
      float pab = fmaf(w2a, gf(a0), w2b*gf(a1));
      float pl  = lv*lv;
      #pragma unroll
      for (int m=1;m<16;m<<=1){ pab += __shfl_xor(pab,m); pl += __shfl_xor(pl,m); }
      if (c==0){
        float* hb_ = (float*)(lpBase + row*48 + 32);
        hb_[1] = pl;
        hb_[2] = 0.5f*pab;
      }
      ((ushort*)(lpBase))[row*24 + c] = (ushort)f2bf(lv);
      const float a02=a0*a0, a12=a1*a1;
      uvS[row*104 +      c] = (ushort)f2bf(a0);      uvS[row*104 + 16 + c] = (ushort)f2bf(a1);
      uvS[row*104 + 32 + c] = (ushort)f2bf(a02);     uvS[row*104 + 48 + c] = (ushort)f2bf(a12);
      uvS[row*104 + 64 + c] = (ushort)f2bf(a02*a0);  uvS[row*104 + 80 + c] = (ushort)f2bf(a12*a1);
    }
  }
  __syncthreads();   // sync5: tile-1 s-side data ready
  PAIR_PHASE(bs0 + 64)
  #undef PAIR_PHASE
}

extern "C" void kernel_launch(void* const* d_in, const int* in_sizes, int n_in,
                              void* d_out, int out_size, void* d_ws, size_t ws_size,
                              hipStream_t stream) {
  const float* h    = (const float*)d_in[0];
  const float* hsrc = (const float*)d_in[1];
  const float* Wl   = (const float*)d_in[2];
  const float* Wt   = (const float*)d_in[3];
  const float* pw1  = (const float*)d_in[4];
  const float* pb1  = (const float*)d_in[5];
  const float* pw2  = (const float*)d_in[6];
  const float* pb2  = (const float*)d_in[7];
  const float* twq  = (const float*)d_in[8];
  const float* tws  = (const float*)d_in[9];
  const float* twd  = (const float*)d_in[10];
  const float* tb1  = (const float*)d_in[11];
  const float* tw2  = (const float*)d_in[12];
  const float* tb2  = (const float*)d_in[13];
  float* out = (float*)d_out;

  k_all<<<dim3(256,1,1), dim3(512,1,1), 0, stream>>>(
      h,hsrc,Wl,Wt,pw1,pb1,pw2,pb2,twq,tws,twd,tb1,tw2,tb2,out);
}

// Round 16
// 19.282 us; speedup vs baseline: 1.3166x; 1.0784x over previous
//
#include <hip/hip_runtime.h>
#include <math.h>

#define T 512
#define EPS2 1e-4f
#define C0G 0.79788456f      // erf(x/sqrt2) = C0 x + C1 x^3 + C2 x^5 + C3 x^7
#define C1G (-0.13298076f)
#define C2G (0.019947114f)
#define C3G (-0.0023746564f)

typedef __attribute__((ext_vector_type(8))) short s8v;   // 8 bf16
typedef __attribute__((ext_vector_type(4))) float f4v;   // MFMA acc

__device__ __forceinline__ uint f2bf(float x){   // f32 -> bf16 bits, RNE
  uint u = __float_as_uint(x);
  return (u + 0x7FFFu + ((u>>16)&1u)) >> 16;
}
__device__ __forceinline__ uint pk2(float a, float b){ return f2bf(a)|(f2bf(b)<<16); }
__device__ __forceinline__ float bflo(uint u){ return __uint_as_float(u<<16); }
__device__ __forceinline__ float bfhi(uint u){ return __uint_as_float(u & 0xFFFF0000u); }
#define MFMA32 __builtin_amdgcn_mfma_f32_16x16x32_bf16
// truncated gelu core (0.5 applied by caller): gf(x) = x + C0 x^2 + C1 x^4
__device__ __forceinline__ float gf(float x){ float x2=x*x; return x + x2*fmaf(C1G,x2,C0G); }

// Dynamic LDS layout (120128 B = 117.3 KB; 1 block/CU so <160 KB is free).
// NO overlays, NO restaging: everything resident for the whole kernel.
#define L_HA   0        // 16384: t-tile
#define L_HB0  16384    // 16384: s-tile 0
#define L_HB1  32768    // 16384: s-tile 1
#define L_WB   49152    // 21760: 80 x 136 ush (Wl | Wat | Was)
#define L_UVT  70912    // 13312: 64 x 104 ush
#define L_UVS0 84224    // 13312
#define L_UVS1 97536    // 13312
#define L_LPT  110848   // 3072: 64 x 48B (cols 0..15 l-bf16; +32: h2,l2,ab floats)
#define L_LPS0 113920   // 3072
#define L_LPS1 116992   // 3072
#define L_K    120064   // 64
#define L_TOT  120128

// 256 WGs x 512 thr (8 waves), 1 block/CU. Block = 1 t-strip x 128 s-cols.
// 2 barriers total: [stage all + fold] sync [project+pack, wave-local] sync
// [pair phases for both tiles, barrier-free].
__global__ __launch_bounds__(512,1) void k_all(
    const float* __restrict__ h, const float* __restrict__ hsrc,
    const float* __restrict__ Wl, const float* __restrict__ Wt,
    const float* __restrict__ pw1, const float* __restrict__ pb1,
    const float* __restrict__ pw2, const float* __restrict__ pb2,
    const float* __restrict__ twq, const float* __restrict__ tws,
    const float* __restrict__ twd, const float* __restrict__ tb1,
    const float* __restrict__ tw2, const float* __restrict__ tb2,
    float* __restrict__ out)
{
  extern __shared__ __align__(16) char smem[];
  ushort* hA   = (ushort*)(smem + L_HA);
  ushort* hB0  = (ushort*)(smem + L_HB0);
  ushort* hB1  = (ushort*)(smem + L_HB1);
  ushort* Wb   = (ushort*)(smem + L_WB);
  ushort* uvT  = (ushort*)(smem + L_UVT);
  ushort* uvS0 = (ushort*)(smem + L_UVS0);
  ushort* uvS1 = (ushort*)(smem + L_UVS1);

  const int tid = threadIdx.x;
  const int Lb  = blockIdx.x;
  const int blk = ((Lb & 7) << 5) | (Lb >> 3);   // XCD-affinity swizzle (256 WGs)
  const int b   = blk >> 5;
  const int bt  = ((blk >> 2) & 7) * 64;
  const int bs0 = (blk & 3) * 128;
  const int lane = tid & 63, wv = tid >> 6;
  const int hi = lane >> 4, c = lane & 15;
  const int sside = wv >> 2, strip = wv & 3, q0 = sside*2;

  // ================= P0a: coalesced staging of ALL THREE tiles =============
  #pragma unroll
  for (int it=0; it<6; ++it){
    const int i = tid + it*512;
    const int tile = i >> 10, i1 = i & 1023;
    const int row = i1 >> 4, cid = i1 & 15;
    const int kk = cid >> 2, h2 = cid & 3;
    const float* base = (tile==0) ? h + (unsigned)(b*T + bt)*128u
                                  : hsrc + (unsigned)(b*T + bs0 + (tile==2?64:0))*128u;
    const float4* src = (const float4*)(base + (unsigned)row*128u + kk*32 + h2*8);
    const float4 a0 = src[0], a1 = src[1];
    uint4 v; v.x=pk2(a0.x,a0.y); v.y=pk2(a0.z,a0.w); v.z=pk2(a1.x,a1.y); v.w=pk2(a1.z,a1.w);
    ushort* dst = (tile==0) ? hA : (tile==1 ? hB0 : hB1);
    *(uint4*)(dst + ((row>>4)*256 + kk*64 + h2*16 + (row&15))*8) = v;
  }
  // ================= P0b: Wl pack + fold into LDS Wb =======================
  if (tid < 256){
    const int j = tid>>4, k0 = (tid&15)*8;
    const float4* src = (const float4*)(Wl + j*128 + k0);
    const float4 b0 = src[0], b1 = src[1];
    uint4 v; v.x=pk2(b0.x,b0.y); v.y=pk2(b0.z,b0.w); v.z=pk2(b1.x,b1.y); v.w=pk2(b1.z,b1.w);
    *(uint4*)(Wb + j*136 + k0) = v;
  }
  {
    const int sideF = tid>>8, j=(tid>>3)&31, k0=(tid&7)*16;
    float tw[8];
    #pragma unroll
    for (int m=0;m<8;m++){
      const float d = twd[j*8+m];
      tw[m] = sideF ? (tws[j*8+m]-d) : (twq[j*8+m]+d);
    }
    float o[16];
    #pragma unroll
    for (int i=0;i<16;i++) o[i]=0.f;
    #pragma unroll
    for (int m=0;m<8;m++){
      const float4* wr = (const float4*)(Wt + m*128 + k0);
      #pragma unroll
      for (int g=0; g<4; ++g){
        const float4 qv = wr[g];
        o[g*4+0]=fmaf(tw[m],qv.x,o[g*4+0]); o[g*4+1]=fmaf(tw[m],qv.y,o[g*4+1]);
        o[g*4+2]=fmaf(tw[m],qv.z,o[g*4+2]); o[g*4+3]=fmaf(tw[m],qv.w,o[g*4+3]);
      }
    }
    ushort* dst = Wb + (16 + sideF*32 + j)*136 + k0;
    uint4 v;
    v.x=pk2(o[0],o[1]); v.y=pk2(o[2],o[3]); v.z=pk2(o[4],o[5]); v.w=pk2(o[6],o[7]);
    *(uint4*)dst = v;
    v.x=pk2(o[8],o[9]); v.y=pk2(o[10],o[11]); v.z=pk2(o[12],o[13]); v.w=pk2(o[14],o[15]);
    *(uint4*)(dst+8) = v;
  }
  __syncthreads();   // sync1: all tiles + Wb ready

  const float w2a = tw2[c], w2b = tw2[c+16];
  const float tb2v = tb2[0];

  // ===== projection + pack helper (wave-local; writes disjoint LDS) ========
  #define PROJ_PACK(SRC_TILE, WROW0, IS_T, UVDST, LPOFF)                        \
  {                                                                             \
    f4v p0={0,0,0,0}, p1={0,0,0,0}, p2={0,0,0,0};                               \
    float nrm = 0.f;                                                            \
    _Pragma("unroll")                                                           \
    for (int kk=0;kk<4;kk++){                                                   \
      union { s8v s; uint4 u; } U;                                              \
      U.s = *(const s8v*)((SRC_TILE) + (strip*256 + kk*64 + lane)*8);           \
      { float x;                                                                \
        x=bflo(U.u.x); nrm=fmaf(x,x,nrm); x=bfhi(U.u.x); nrm=fmaf(x,x,nrm);     \
        x=bflo(U.u.y); nrm=fmaf(x,x,nrm); x=bfhi(U.u.y); nrm=fmaf(x,x,nrm);     \
        x=bflo(U.u.z); nrm=fmaf(x,x,nrm); x=bfhi(U.u.z); nrm=fmaf(x,x,nrm);     \
        x=bflo(U.u.w); nrm=fmaf(x,x,nrm); x=bfhi(U.u.w); nrm=fmaf(x,x,nrm); }   \
      const int ko = kk*32 + hi*8;                                              \
      const s8v bl = *(const s8v*)(Wb + (c)*136 + ko);                          \
      const s8v b0 = *(const s8v*)(Wb + ((WROW0) + c)*136 + ko);                \
      const s8v b1 = *(const s8v*)(Wb + ((WROW0) + 16 + c)*136 + ko);           \
      p0 = MFMA32(U.s, b0, p0,0,0,0);                                           \
      p1 = MFMA32(U.s, b1, p1,0,0,0);                                           \
      p2 = MFMA32(U.s, bl, p2,0,0,0);                                           \
    }                                                                           \
    nrm += __shfl_xor(nrm,16); nrm += __shfl_xor(nrm,32);                       \
    char* lpBase = smem + (LPOFF);                                              \
    if (hi==0) *(float*)(lpBase + (strip*16 + c)*48 + 32) = nrm;                \
    _Pragma("unroll")                                                           \
    for (int r=0;r<4;r++){                                                      \
      const int row = strip*16 + hi*4 + r;                                      \
      const float a0 = p0[r] + ((IS_T) ? tb1[c]    : 0.f);                      \
      const float a1 = p1[r] + ((IS_T) ? tb1[c+16] : 0.f);                      \
      const float lv = p2[r];                                                   \
      float pab = fmaf(w2a, gf(a0), w2b*gf(a1));                                \
      float pl  = lv*lv;                                                        \
      _Pragma("unroll")                                                         \
      for (int m=1;m<16;m<<=1){ pab += __shfl_xor(pab,m); pl += __shfl_xor(pl,m); } \
      if (c==0){                                                                \
        float* hb_ = (float*)(lpBase + row*48 + 32);                            \
        hb_[1] = pl;                                                            \
        hb_[2] = (IS_T) ? fmaf(0.5f, pab, tb2v) : 0.5f*pab;                     \
      }                                                                         \
      ((ushort*)(lpBase))[row*24 + c] = (ushort)f2bf(lv);                       \
      const float a02=a0*a0, a12=a1*a1;                                         \
      if (IS_T){                                                                \
        const float wa0 = w2a*a0, wa1 = w2b*a1;                                 \
        (UVDST)[row*104 +      c] = (ushort)f2bf(wa0*fmaf(2.f*C1G, a02, C0G));  \
        (UVDST)[row*104 + 16 + c] = (ushort)f2bf(wa1*fmaf(2.f*C1G, a12, C0G));  \
        (UVDST)[row*104 + 32 + c] = (ushort)f2bf(3.f*C1G*w2a*a02);              \
        (UVDST)[row*104 + 48 + c] = (ushort)f2bf(3.f*C1G*w2b*a12);              \
        (UVDST)[row*104 + 64 + c] = (ushort)f2bf(2.f*C1G*wa0);                  \
        (UVDST)[row*104 + 80 + c] = (ushort)f2bf(2.f*C1G*wa1);                  \
      } else {                                                                  \
        (UVDST)[row*104 +      c] = (ushort)f2bf(a0);                           \
        (UVDST)[row*104 + 16 + c] = (ushort)f2bf(a1);                           \
        (UVDST)[row*104 + 32 + c] = (ushort)f2bf(a02);                          \
        (UVDST)[row*104 + 48 + c] = (ushort)f2bf(a12);                          \
        (UVDST)[row*104 + 64 + c] = (ushort)f2bf(a02*a0);                       \
        (UVDST)[row*104 + 80 + c] = (ushort)f2bf(a12*a1);                       \
      }                                                                         \
    }                                                                           \
  }

  // pass 1: waves 0-3 -> t-strips; waves 4-7 -> s0-strips
  if (sside == 0){
    PROJ_PACK(hA, 16, 1, uvT, L_LPT)
  } else {
    PROJ_PACK(hB0, 48, 0, uvS0, L_LPS0)
  }
  // pass 2: waves 0-3 -> s1-strips; wave 4 -> K poly
  if (sside == 0){
    PROJ_PACK(hB1, 48, 0, uvS1, L_LPS1)
  } else if (wv == 4){
    const int lj = lane & 31;
    const float kw = (lane < 32) ? (0.5f * pw2[lj]) : 0.f;
    const float bb = pb1[lj], mm = pw1[lj];
    float bp[9], mp[9];
    bp[0]=1.f; mp[0]=1.f;
    #pragma unroll
    for (int i=1;i<9;i++){ bp[i]=bp[i-1]*bb; mp[i]=mp[i-1]*mm; }
    float Kq[9];
    Kq[0] = kw*(bb + C0G*bp[2] + C1G*bp[4] + C2G*bp[6] + C3G*bp[8]);
    Kq[1] = kw*mp[1]*(1.f + 2.f*C0G*bp[1] + 4.f*C1G*bp[3] + 6.f*C2G*bp[5] + 8.f*C3G*bp[7]);
    Kq[2] = kw*mp[2]*(C0G + 6.f*C1G*bp[2] + 15.f*C2G*bp[4] + 28.f*C3G*bp[6]);
    Kq[3] = kw*mp[3]*(4.f*C1G*bp[1] + 20.f*C2G*bp[3] + 56.f*C3G*bp[5]);
    Kq[4] = kw*mp[4]*(C1G + 15.f*C2G*bp[2] + 70.f*C3G*bp[4]);
    Kq[5] = kw*mp[5]*(6.f*C2G*bp[1] + 56.f*C3G*bp[3]);
    Kq[6] = kw*mp[6]*(C2G + 28.f*C3G*bp[2]);
    Kq[7] = kw*mp[7]*(8.f*C3G*bp[1]);
    Kq[8] = kw*mp[8]*C3G;
    #pragma unroll
    for (int m=1;m<64;m<<=1){
      #pragma unroll
      for (int i=0;i<9;i++) Kq[i] += __shfl_xor(Kq[i], m);
    }
    if (lane==0){
      Kq[0] += pb2[0];
      #pragma unroll
      for (int i=0;i<9;i++) ((float*)(smem+L_K))[i] = Kq[i];
    }
  }
  #undef PROJ_PACK
  __syncthreads();   // sync2: all row data + K published

  float K[9];
  #pragma unroll
  for (int i=0;i<9;i++) K[i] = ((const float*)(smem+L_K))[i];
  s8v ah[4];
  #pragma unroll
  for (int kk=0;kk<4;kk++) ah[kk] = *(const s8v*)(hA + (strip*256 + kk*64 + lane)*8);

  // ================= pair phases (barrier-free, both tiles resident) =======
  #define PAIR_PHASE(HBX, UVSX, LPSOFF, BS)                                     \
  {                                                                             \
    f4v acch[2], accz[2], accl[2];                                              \
    _Pragma("unroll")                                                           \
    for (int qq=0;qq<2;qq++){ acch[qq]=(f4v){0,0,0,0}; accz[qq]=(f4v){0,0,0,0}; accl[qq]=(f4v){0,0,0,0}; } \
    _Pragma("unroll")                                                           \
    for (int kk=0;kk<4;kk++){                                                   \
      _Pragma("unroll")                                                         \
      for (int qq=0;qq<2;qq++)                                                  \
        acch[qq] = MFMA32(ah[kk], *(const s8v*)((HBX) + ((q0+qq)*256 + kk*64 + lane)*8), acch[qq],0,0,0); \
    }                                                                           \
    _Pragma("unroll")                                                           \
    for (int ks=0;ks<3;ks++){                                                   \
      const s8v au = *(const s8v*)(uvT + (strip*16 + c)*104 + ks*32 + hi*8);    \
      _Pragma("unroll")                                                         \
      for (int qq=0;qq<2;qq++)                                                  \
        accz[qq] = MFMA32(au, *(const s8v*)((UVSX) + ((q0+qq)*16 + c)*104 + ks*32 + hi*8), accz[qq],0,0,0); \
    }                                                                           \
    {                                                                           \
      union { uint4 u; s8v s; } Z; Z.u = make_uint4(0,0,0,0);                   \
      const s8v al_ = (hi<2) ? *(const s8v*)(smem + L_LPT + (strip*16+c)*48 + hi*16) : Z.s; \
      _Pragma("unroll")                                                         \
      for (int qq=0;qq<2;qq++){                                                 \
        const s8v bq = (hi<2) ? *(const s8v*)(smem + (LPSOFF) + ((q0+qq)*16+c)*48 + hi*16) : Z.s; \
        accl[qq] = MFMA32(al_, bq, accl[qq],0,0,0);                             \
      }                                                                         \
    }                                                                           \
    float h2t[4], l2t[4], alv[4];                                               \
    _Pragma("unroll")                                                           \
    for (int r=0;r<4;r++){                                                      \
      const float* th_ = (const float*)(smem + L_LPT + (strip*16 + hi*4 + r)*48 + 32); \
      h2t[r]=th_[0]; l2t[r]=th_[1]; alv[r]=th_[2];                              \
    }                                                                           \
    _Pragma("unroll")                                                           \
    for (int qq=0;qq<2;qq++){                                                   \
      const int sidx = (q0+qq)*16 + c;                                          \
      const float* sh_ = (const float*)(smem + (LPSOFF) + sidx*48 + 32);        \
      const float h2s=sh_[0], l2s=sh_[1], bet=sh_[2];                           \
      _Pragma("unroll")                                                         \
      for (int r=0;r<4;r++){                                                    \
        const float d2 = fmaxf(fmaf(-2.f, acch[qq][r], h2t[r] + h2s), 0.f);     \
        const float ir = rsqrtf(d2 + EPS2);                                     \
        const float l2 = fmaxf(fmaf(-2.f, accl[qq][r], l2t[r] + l2s), 0.f);     \
        const float lam = fminf(l2, 16.f);                                      \
        float zc = K[8];                                                        \
        _Pragma("unroll")                                                       \
        for (int i=7;i>=0;i--) zc = fmaf(zc, lam, K[i]);                        \
        const float cc  = __logf(1.f + __expf(zc));                             \
        const float phi = __expf(-cc * l2);                                     \
        const float z   = accz[qq][r] + alv[r] + bet;                           \
        const float th  = z * fmaf(z*z, -0.33333334f, 1.f);                     \
        __builtin_nontemporal_store(-th * phi * ir,                             \
          out + (unsigned)(b*T + bt + strip*16 + hi*4 + r)*T + (BS) + sidx);    \
      }                                                                         \
    }                                                                           \
  }

  PAIR_PHASE(hB0, uvS0, L_LPS0, bs0)
  PAIR_PHASE(hB1, uvS1, L_LPS1, bs0 + 64)
  #undef PAIR_PHASE
}

extern "C" void kernel_launch(void* const* d_in, const int* in_sizes, int n_in,
                              void* d_out, int out_size, void* d_ws, size_t ws_size,
                              hipStream_t stream) {
  const float* h    = (const float*)d_in[0];
  const float* hsrc = (const float*)d_in[1];
  const float* Wl   = (const float*)d_in[2];
  const float* Wt   = (const float*)d_in[3];
  const float* pw1  = (const float*)d_in[4];
  const float* pb1  = (const float*)d_in[5];
  const float* pw2  = (const float*)d_in[6];
  const float* pb2  = (const float*)d_in[7];
  const float* twq  = (const float*)d_in[8];
  const float* tws  = (const float*)d_in[9];
  const float* twd  = (const float*)d_in[10];
  const float* tb1  = (const float*)d_in[11];
  const float* tw2  = (const float*)d_in[12];
  const float* tb2  = (const float*)d_in[13];
  float* out = (float*)d_out;

  hipFuncSetAttribute((const void*)k_all,
                      hipFuncAttributeMaxDynamicSharedMemorySize, L_TOT);
  k_all<<<dim3(256,1,1), dim3(512,1,1), L_TOT, stream>>>(
      h,hsrc,Wl,Wt,pw1,pb1,pw2,pb2,twq,tws,twd,tb1,tw2,tb2,out);
}

// Round 17
// 18.944 us; speedup vs baseline: 1.3401x; 1.0178x over previous
//
#include <hip/hip_runtime.h>
#include <hip/hip_bf16.h>
#include <math.h>

#define T 512
#define EPS2 1e-4f
#define C0G 0.79788456f      // erf(x/sqrt2) = C0 x + C1 x^3 + C2 x^5 + C3 x^7
#define C1G (-0.13298076f)
#define C2G (0.019947114f)
#define C3G (-0.0023746564f)

typedef __attribute__((ext_vector_type(8))) short s8v;   // 8 bf16
typedef __attribute__((ext_vector_type(4))) float f4v;   // MFMA acc

// HW-converted packs (compiler emits v_cvt_pk_bf16_f32 / v_cvt variants)
__device__ __forceinline__ uint pk2(float a, float b){
  __hip_bfloat162 t = __float22bfloat162_rn(make_float2(a, b));
  return *reinterpret_cast<uint*>(&t);
}
__device__ __forceinline__ ushort f2bf(float x){
  __hip_bfloat16 t = __float2bfloat16(x);
  return *reinterpret_cast<ushort*>(&t);
}
__device__ __forceinline__ float bflo(uint u){ return __uint_as_float(u<<16); }
__device__ __forceinline__ float bfhi(uint u){ return __uint_as_float(u & 0xFFFF0000u); }
#define MFMA32 __builtin_amdgcn_mfma_f32_16x16x32_bf16
// truncated gelu core (0.5 applied by caller): gf(x) = x + C0 x^2 + C1 x^4
__device__ __forceinline__ float gf(float x){ float x2=x*x; return x + x2*fmaf(C1G,x2,C0G); }

// Dynamic LDS layout (120128 B; 1 block/CU so <160 KB is free).
#define L_HA   0        // 16384: t-tile
#define L_HB0  16384    // 16384: s-tile 0
#define L_HB1  32768    // 16384: s-tile 1
#define L_WB   49152    // 21760: 80 x 136 ush (Wl | Wat | Was)
#define L_UVT  70912    // 13312: 64 x 104 ush
#define L_UVS0 84224    // 13312
#define L_UVS1 97536    // 13312
#define L_LPT  110848   // 3072: 64 x 48B (cols 0..15 l-bf16; +32: h2,l2,ab floats)
#define L_LPS0 113920   // 3072
#define L_LPS1 116992   // 3072
#define L_K    120064   // 64
#define L_TOT  120128

// 256 WGs x 512 thr (8 waves), 1 block/CU. Block = 1 t-strip x 128 s-cols.
// 2 barriers: [stage all + fold] sync [project+pack wave-local] sync [pairs].
// uv packs use the k-permutation trick: dims interleaved as (unit c, unit 16+c)
// pairs on BOTH sides -> dot unchanged, but writes become paired uint stores.
__global__ __launch_bounds__(512,1) void k_all(
    const float* __restrict__ h, const float* __restrict__ hsrc,
    const float* __restrict__ Wl, const float* __restrict__ Wt,
    const float* __restrict__ pw1, const float* __restrict__ pb1,
    const float* __restrict__ pw2, const float* __restrict__ pb2,
    const float* __restrict__ twq, const float* __restrict__ tws,
    const float* __restrict__ twd, const float* __restrict__ tb1,
    const float* __restrict__ tw2, const float* __restrict__ tb2,
    float* __restrict__ out)
{
  extern __shared__ __align__(16) char smem[];
  ushort* hA   = (ushort*)(smem + L_HA);
  ushort* hB0  = (ushort*)(smem + L_HB0);
  ushort* hB1  = (ushort*)(smem + L_HB1);
  ushort* Wb   = (ushort*)(smem + L_WB);
  ushort* uvT  = (ushort*)(smem + L_UVT);
  ushort* uvS0 = (ushort*)(smem + L_UVS0);
  ushort* uvS1 = (ushort*)(smem + L_UVS1);

  const int tid = threadIdx.x;
  const int Lb  = blockIdx.x;
  const int blk = ((Lb & 7) << 5) | (Lb >> 3);   // XCD-affinity swizzle (256 WGs)
  const int b   = blk >> 5;
  const int bt  = ((blk >> 2) & 7) * 64;
  const int bs0 = (blk & 3) * 128;
  const int lane = tid & 63, wv = tid >> 6;
  const int hi = lane >> 4, c = lane & 15;
  const int sside = wv >> 2, strip = wv & 3, q0 = sside*2;

  // ================= P0a: coalesced staging of ALL THREE tiles =============
  #pragma unroll
  for (int it=0; it<6; ++it){
    const int i = tid + it*512;
    const int tile = i >> 10, i1 = i & 1023;
    const int row = i1 >> 4, cid = i1 & 15;
    const int kk = cid >> 2, h2 = cid & 3;
    const float* base = (tile==0) ? h + (unsigned)(b*T + bt)*128u
                                  : hsrc + (unsigned)(b*T + bs0 + (tile==2?64:0))*128u;
    const float4* src = (const float4*)(base + (unsigned)row*128u + kk*32 + h2*8);
    const float4 a0 = src[0], a1 = src[1];
    uint4 v; v.x=pk2(a0.x,a0.y); v.y=pk2(a0.z,a0.w); v.z=pk2(a1.x,a1.y); v.w=pk2(a1.z,a1.w);
    ushort* dst = (tile==0) ? hA : (tile==1 ? hB0 : hB1);
    *(uint4*)(dst + ((row>>4)*256 + kk*64 + h2*16 + (row&15))*8) = v;
  }
  // ================= P0b: Wl pack + fold into LDS Wb =======================
  if (tid < 256){
    const int j = tid>>4, k0 = (tid&15)*8;
    const float4* src = (const float4*)(Wl + j*128 + k0);
    const float4 b0 = src[0], b1 = src[1];
    uint4 v; v.x=pk2(b0.x,b0.y); v.y=pk2(b0.z,b0.w); v.z=pk2(b1.x,b1.y); v.w=pk2(b1.z,b1.w);
    *(uint4*)(Wb + j*136 + k0) = v;
  }
  {
    const int sideF = tid>>8, j=(tid>>3)&31, k0=(tid&7)*16;
    float tw[8];
    #pragma unroll
    for (int m=0;m<8;m++){
      const float d = twd[j*8+m];
      tw[m] = sideF ? (tws[j*8+m]-d) : (twq[j*8+m]+d);
    }
    float o[16];
    #pragma unroll
    for (int i=0;i<16;i++) o[i]=0.f;
    #pragma unroll
    for (int m=0;m<8;m++){
      const float4* wr = (const float4*)(Wt + m*128 + k0);
      #pragma unroll
      for (int g=0; g<4; ++g){
        const float4 qv = wr[g];
        o[g*4+0]=fmaf(tw[m],qv.x,o[g*4+0]); o[g*4+1]=fmaf(tw[m],qv.y,o[g*4+1]);
        o[g*4+2]=fmaf(tw[m],qv.z,o[g*4+2]); o[g*4+3]=fmaf(tw[m],qv.w,o[g*4+3]);
      }
    }
    ushort* dst = Wb + (16 + sideF*32 + j)*136 + k0;
    uint4 v;
    v.x=pk2(o[0],o[1]); v.y=pk2(o[2],o[3]); v.z=pk2(o[4],o[5]); v.w=pk2(o[6],o[7]);
    *(uint4*)dst = v;
    v.x=pk2(o[8],o[9]); v.y=pk2(o[10],o[11]); v.z=pk2(o[12],o[13]); v.w=pk2(o[14],o[15]);
    *(uint4*)(dst+8) = v;
  }
  __syncthreads();   // sync1: all tiles + Wb ready

  const float w2a = tw2[c], w2b = tw2[c+16];
  const float tb2v = tb2[0];

  // ===== projection + pack helper (wave-local; writes disjoint LDS) ========
  #define PROJ_PACK(SRC_TILE, WROW0, IS_T, UVDST, LPOFF)                        \
  {                                                                             \
    f4v p0={0,0,0,0}, p1={0,0,0,0}, p2={0,0,0,0};                               \
    float nrm = 0.f;                                                            \
    _Pragma("unroll")                                                           \
    for (int kk=0;kk<4;kk++){                                                   \
      union { s8v s; uint4 u; } U;                                              \
      U.s = *(const s8v*)((SRC_TILE) + (strip*256 + kk*64 + lane)*8);           \
      { float x;                                                                \
        x=bflo(U.u.x); nrm=fmaf(x,x,nrm); x=bfhi(U.u.x); nrm=fmaf(x,x,nrm);     \
        x=bflo(U.u.y); nrm=fmaf(x,x,nrm); x=bfhi(U.u.y); nrm=fmaf(x,x,nrm);     \
        x=bflo(U.u.z); nrm=fmaf(x,x,nrm); x=bfhi(U.u.z); nrm=fmaf(x,x,nrm);     \
        x=bflo(U.u.w); nrm=fmaf(x,x,nrm); x=bfhi(U.u.w); nrm=fmaf(x,x,nrm); }   \
      const int ko = kk*32 + hi*8;                                              \
      const s8v bl = *(const s8v*)(Wb + (c)*136 + ko);                          \
      const s8v b0 = *(const s8v*)(Wb + ((WROW0) + c)*136 + ko);                \
      const s8v b1 = *(const s8v*)(Wb + ((WROW0) + 16 + c)*136 + ko);           \
      p0 = MFMA32(U.s, b0, p0,0,0,0);                                           \
      p1 = MFMA32(U.s, b1, p1,0,0,0);                                           \
      p2 = MFMA32(U.s, bl, p2,0,0,0);                                           \
    }                                                                           \
    nrm += __shfl_xor(nrm,16); nrm += __shfl_xor(nrm,32);                       \
    char* lpBase = smem + (LPOFF);                                              \
    if (hi==0) *(float*)(lpBase + (strip*16 + c)*48 + 32) = nrm;                \
    _Pragma("unroll")                                                           \
    for (int r=0;r<4;r++){                                                      \
      const int row = strip*16 + hi*4 + r;                                      \
      const float a0 = p0[r] + ((IS_T) ? tb1[c]    : 0.f);                      \
      const float a1 = p1[r] + ((IS_T) ? tb1[c+16] : 0.f);                      \
      const float lv = p2[r];                                                   \
      float pab = fmaf(w2a, gf(a0), w2b*gf(a1));                                \
      float pl  = lv*lv;                                                        \
      _Pragma("unroll")                                                         \
      for (int m=1;m<16;m<<=1){ pab += __shfl_xor(pab,m); pl += __shfl_xor(pl,m); } \
      if (c==0){                                                                \
        float* hb_ = (float*)(lpBase + row*48 + 32);                            \
        hb_[1] = pl;                                                            \
        hb_[2] = (IS_T) ? fmaf(0.5f, pab, tb2v) : 0.5f*pab;                     \
      }                                                                         \
      ((ushort*)(lpBase))[row*24 + c] = f2bf(lv);                               \
      const float a02=a0*a0, a12=a1*a1;                                         \
      if (IS_T){                                                                \
        const float wa0 = w2a*a0, wa1 = w2b*a1;                                 \
        *(uint*)((UVDST) + row*104 +      2*c) = pk2(wa0*fmaf(2.f*C1G, a02, C0G), \
                                                     wa1*fmaf(2.f*C1G, a12, C0G)); \
        *(uint*)((UVDST) + row*104 + 32 + 2*c) = pk2(3.f*C1G*w2a*a02, 3.f*C1G*w2b*a12); \
        *(uint*)((UVDST) + row*104 + 64 + 2*c) = pk2(2.f*C1G*wa0, 2.f*C1G*wa1); \
      } else {                                                                  \
        *(uint*)((UVDST) + row*104 +      2*c) = pk2(a0, a1);                   \
        *(uint*)((UVDST) + row*104 + 32 + 2*c) = pk2(a02, a12);                 \
        *(uint*)((UVDST) + row*104 + 64 + 2*c) = pk2(a02*a0, a12*a1);           \
      }                                                                         \
    }                                                                           \
  }

  // pass 1: waves 0-3 -> t-strips; waves 4-7 -> s0-strips
  if (sside == 0){
    PROJ_PACK(hA, 16, 1, uvT, L_LPT)
  } else {
    PROJ_PACK(hB0, 48, 0, uvS0, L_LPS0)
  }
  // pass 2: waves 0-3 -> s1-strips; wave 4 -> K poly
  if (sside == 0){
    PROJ_PACK(hB1, 48, 0, uvS1, L_LPS1)
  } else if (wv == 4){
    const int lj = lane & 31;
    const float kw = (lane < 32) ? (0.5f * pw2[lj]) : 0.f;
    const float bb = pb1[lj], mm = pw1[lj];
    float bp[9], mp[9];
    bp[0]=1.f; mp[0]=1.f;
    #pragma unroll
    for (int i=1;i<9;i++){ bp[i]=bp[i-1]*bb; mp[i]=mp[i-1]*mm; }
    float Kq[9];
    Kq[0] = kw*(bb + C0G*bp[2] + C1G*bp[4] + C2G*bp[6] + C3G*bp[8]);
    Kq[1] = kw*mp[1]*(1.f + 2.f*C0G*bp[1] + 4.f*C1G*bp[3] + 6.f*C2G*bp[5] + 8.f*C3G*bp[7]);
    Kq[2] = kw*mp[2]*(C0G + 6.f*C1G*bp[2] + 15.f*C2G*bp[4] + 28.f*C3G*bp[6]);
    Kq[3] = kw*mp[3]*(4.f*C1G*bp[1] + 20.f*C2G*bp[3] + 56.f*C3G*bp[5]);
    Kq[4] = kw*mp[4]*(C1G + 15.f*C2G*bp[2] + 70.f*C3G*bp[4]);
    Kq[5] = kw*mp[5]*(6.f*C2G*bp[1] + 56.f*C3G*bp[3]);
    Kq[6] = kw*mp[6]*(C2G + 28.f*C3G*bp[2]);
    Kq[7] = kw*mp[7]*(8.f*C3G*bp[1]);
    Kq[8] = kw*mp[8]*C3G;
    #pragma unroll
    for (int m=1;m<64;m<<=1){
      #pragma unroll
      for (int i=0;i<9;i++) Kq[i] += __shfl_xor(Kq[i], m);
    }
    if (lane==0){
      Kq[0] += pb2[0];
      #pragma unroll
      for (int i=0;i<9;i++) ((float*)(smem+L_K))[i] = Kq[i];
    }
  }
  #undef PROJ_PACK
  __syncthreads();   // sync2: all row data + K published

  float K[9];
  #pragma unroll
  for (int i=0;i<9;i++) K[i] = ((const float*)(smem+L_K))[i];
  s8v ah[4];
  #pragma unroll
  for (int kk=0;kk<4;kk++) ah[kk] = *(const s8v*)(hA + (strip*256 + kk*64 + lane)*8);

  // ================= pair phases (barrier-free, both tiles resident) =======
  #define PAIR_PHASE(HBX, UVSX, LPSOFF, BS)                                     \
  {                                                                             \
    f4v acch[2], accz[2], accl[2];                                              \
    _Pragma("unroll")                                                           \
    for (int qq=0;qq<2;qq++){ acch[qq]=(f4v){0,0,0,0}; accz[qq]=(f4v){0,0,0,0}; accl[qq]=(f4v){0,0,0,0}; } \
    _Pragma("unroll")                                                           \
    for (int kk=0;kk<4;kk++){                                                   \
      _Pragma("unroll")                                                         \
      for (int qq=0;qq<2;qq++)                                                  \
        acch[qq] = MFMA32(ah[kk], *(const s8v*)((HBX) + ((q0+qq)*256 + kk*64 + lane)*8), acch[qq],0,0,0); \
    }                                                                           \
    _Pragma("unroll")                                                           \
    for (int ks=0;ks<3;ks++){                                                   \
      const s8v au = *(const s8v*)(uvT + (strip*16 + c)*104 + ks*32 + hi*8);    \
      _Pragma("unroll")                                                         \
      for (int qq=0;qq<2;qq++)                                                  \
        accz[qq] = MFMA32(au, *(const s8v*)((UVSX) + ((q0+qq)*16 + c)*104 + ks*32 + hi*8), accz[qq],0,0,0); \
    }                                                                           \
    {                                                                           \
      union { uint4 u; s8v s; } Z; Z.u = make_uint4(0,0,0,0);                   \
      const s8v al_ = (hi<2) ? *(const s8v*)(smem + L_LPT + (strip*16+c)*48 + hi*16) : Z.s; \
      _Pragma("unroll")                                                         \
      for (int qq=0;qq<2;qq++){                                                 \
        const s8v bq = (hi<2) ? *(const s8v*)(smem + (LPSOFF) + ((q0+qq)*16+c)*48 + hi*16) : Z.s; \
        accl[qq] = MFMA32(al_, bq, accl[qq],0,0,0);                             \
      }                                                                         \
    }                                                                           \
    float h2t[4], l2t[4], alv[4];                                               \
    _Pragma("unroll")                                                           \
    for (int r=0;r<4;r++){                                                      \
      const float* th_ = (const float*)(smem + L_LPT + (strip*16 + hi*4 + r)*48 + 32); \
      h2t[r]=th_[0]; l2t[r]=th_[1]; alv[r]=th_[2];                              \
    }                                                                           \
    _Pragma("unroll")                                                           \
    for (int qq=0;qq<2;qq++){                                                   \
      const int sidx = (q0+qq)*16 + c;                                          \
      const float* sh_ = (const float*)(smem + (LPSOFF) + sidx*48 + 32);        \
      const float h2s=sh_[0], l2s=sh_[1], bet=sh_[2];                           \
      _Pragma("unroll")                                                         \
      for (int r=0;r<4;r++){                                                    \
        const float d2 = fmaxf(fmaf(-2.f, acch[qq][r], h2t[r] + h2s), 0.f);     \
        const float ir = rsqrtf(d2 + EPS2);                                     \
        const float l2 = fmaxf(fmaf(-2.f, accl[qq][r], l2t[r] + l2s), 0.f);     \
        const float lam = fminf(l2, 16.f);                                      \
        float zc = K[8];                                                        \
        _Pragma("unroll")                                                       \
        for (int i=7;i>=0;i--) zc = fmaf(zc, lam, K[i]);                        \
        const float cc  = __logf(1.f + __expf(zc));                             \
        const float phi = __expf(-cc * l2);                                     \
        const float z   = accz[qq][r] + alv[r] + bet;                           \
        const float th  = z * fmaf(z*z, -0.33333334f, 1.f);                     \
        __builtin_nontemporal_store(-th * phi * ir,                             \
          out + (unsigned)(b*T + bt + strip*16 + hi*4 + r)*T + (BS) + sidx);    \
      }                                                                         \
    }                                                                           \
  }

  PAIR_PHASE(hB0, uvS0, L_LPS0, bs0)
  PAIR_PHASE(hB1, uvS1, L_LPS1, bs0 + 64)
  #undef PAIR_PHASE
}

extern "C" void kernel_launch(void* const* d_in, const int* in_sizes, int n_in,
                              void* d_out, int out_size, void* d_ws, size_t ws_size,
                              hipStream_t stream) {
  const float* h    = (const float*)d_in[0];
  const float* hsrc = (const float*)d_in[1];
  const float* Wl   = (const float*)d_in[2];
  const float* Wt   = (const float*)d_in[3];
  const float* pw1  = (const float*)d_in[4];
  const float* pb1  = (const float*)d_in[5];
  const float* pw2  = (const float*)d_in[6];
  const float* pb2  = (const float*)d_in[7];
  const float* twq  = (const float*)d_in[8];
  const float* tws  = (const float*)d_in[9];
  const float* twd  = (const float*)d_in[10];
  const float* tb1  = (const float*)d_in[11];
  const float* tw2  = (const float*)d_in[12];
  const float* tb2  = (const float*)d_in[13];
  float* out = (float*)d_out;

  hipFuncSetAttribute((const void*)k_all,
                      hipFuncAttributeMaxDynamicSharedMemorySize, L_TOT);
  k_all<<<dim3(256,1,1), dim3(512,1,1), L_TOT, stream>>>(
      h,hsrc,Wl,Wt,pw1,pb1,pw2,pb2,twq,tws,twd,tb1,tw2,tb2,out);
}